// Round 1
// baseline (1765.727 us; speedup 1.0000x reference)
//
#include <hip/hip_runtime.h>
#include <hip/hip_bf16.h>
#include <cstdint>
#include <cstddef>

// Problem constants
#define BB 2
#define SS 2048
#define EE 1024
#define HH 16
#define DH 64
#define KKSEL 409   // kk = int(2048*0.2)
#define QT 8        // query rows per attention block

__device__ __forceinline__ unsigned sortkey(float f){
    unsigned u = __float_as_uint(f);
    // monotone map: f1 >= f2  <=>  sortkey(f1) >= sortkey(f2)
    return (u & 0x80000000u) ? ~u : (u | 0x80000000u);
}

// ---------------------------------------------------------------------------
// Tiled fp32 GEMM: C = X(4096x1024) @ W(1024x1024) + bias
// MODE 0: write Q as [bh][s][d]
// MODE 1: write K transposed [bh][d][s], scaled by time_scales[h]
// MODE 2: write V as [bh][s][d]
// MODE 3: plain row-major write (final projection -> d_out)
// 64x64 tile, 256 threads, 4x4 microtile, BK=16.
// ---------------------------------------------------------------------------
template<int MODE>
__global__ __launch_bounds__(256) void gemm_proj(const float* __restrict__ X,
                                                 const float* __restrict__ W,
                                                 const float* __restrict__ bias,
                                                 const float* __restrict__ ts,
                                                 float* __restrict__ Out)
{
    __shared__ float As[16][68];  // [k][m], padded row so float4 stays 16B aligned
    __shared__ float Bs[16][64];  // [k][n]
    const int tid = threadIdx.x;
    const int m0 = blockIdx.y * 64;
    const int n0 = blockIdx.x * 64;
    const int ty = tid >> 4, tx = tid & 15;
    const int am = tid >> 2, ak = (tid & 3) * 4;       // A tile load coords
    const int bk = tid >> 4, bn = (tid & 15) * 4;      // B tile load coords
    float acc[4][4] = {};

    for (int k0 = 0; k0 < EE; k0 += 16){
        float4 av = *(const float4*)&X[(size_t)(m0 + am) * EE + k0 + ak];
        As[ak + 0][am] = av.x; As[ak + 1][am] = av.y;
        As[ak + 2][am] = av.z; As[ak + 3][am] = av.w;
        *(float4*)&Bs[bk][bn] = *(const float4*)&W[(size_t)(k0 + bk) * EE + n0 + bn];
        __syncthreads();
        #pragma unroll
        for (int k = 0; k < 16; ++k){
            float4 fa = *(const float4*)&As[k][ty * 4];
            float4 fb = *(const float4*)&Bs[k][tx * 4];
            float a[4] = {fa.x, fa.y, fa.z, fa.w};
            float b[4] = {fb.x, fb.y, fb.z, fb.w};
            #pragma unroll
            for (int i = 0; i < 4; ++i)
                #pragma unroll
                for (int j = 0; j < 4; ++j)
                    acc[i][j] = fmaf(a[i], b[j], acc[i][j]);
        }
        __syncthreads();
    }

    #pragma unroll
    for (int i = 0; i < 4; ++i){
        const int m = m0 + ty * 4 + i;
        #pragma unroll
        for (int j = 0; j < 4; ++j){
            const int n = n0 + tx * 4 + j;
            float v = acc[i][j] + bias[n];
            if (MODE == 3){
                Out[(size_t)m * EE + n] = v;
            } else {
                const int b = m >> 11, s = m & (SS - 1);
                const int h = n >> 6,  d = n & (DH - 1);
                if (MODE == 1){
                    v *= ts[h];
                    Out[(((size_t)(b * HH + h)) * DH + d) * SS + s] = v;   // K^T
                } else {
                    Out[(((size_t)(b * HH + h)) * SS + s) * DH + d] = v;
                }
            }
        }
    }
}

// ---------------------------------------------------------------------------
// Fused attention: scores -> scale -> diag boost -> exact top-k (radix select)
// -> mask boost -> softmax -> P@V.  One block = 8 query rows of one (b,h).
// Scores live in registers: thread owns cols [tid*8, tid*8+8) for all 8 rows.
// ---------------------------------------------------------------------------
union ShMem {
    unsigned hist[QT][257];        // radix-select histograms (row-padded)
    float    red2[4][QT][DH];      // cross-wave reduction for P@V
};

__global__ __launch_bounds__(256) void attn_kernel(const float* __restrict__ Q,
                                                   const float* __restrict__ Kt,
                                                   const float* __restrict__ V,
                                                   float* __restrict__ AO)
{
    __shared__ float qst[DH][QT];                 // q tile transposed [d][r]
    __shared__ __hip_bfloat16 probs[QT][SS];      // 32 KB
    __shared__ ShMem su;                          // 8.2 KB
    __shared__ float redw[QT][4];
    __shared__ unsigned selbin[QT];
    __shared__ unsigned selkk[QT];

    const int tid  = threadIdx.x;
    const int lane = tid & 63;
    const int wave = tid >> 6;
    const int nt = SS / QT;                        // 256 tiles per (b,h)
    const int bh = blockIdx.x / nt;
    const int t0 = (blockIdx.x % nt) * QT;
    const float* Qb  = Q  + (size_t)bh * SS * DH;
    const float* Ktb = Kt + (size_t)bh * DH * SS;
    const float* Vb  = V  + (size_t)bh * SS * DH;

    for (int l = tid; l < QT * DH; l += 256){
        const int r = l >> 6, d = l & 63;
        qst[d][r] = Qb[(size_t)(t0 + r) * DH + d];
    }
    __syncthreads();

    // ---- phase 1: score GEMM (8 rows x 8 cols per thread) ----
    const int c0 = tid * 8;
    float acc[QT][8];
    #pragma unroll
    for (int r = 0; r < QT; ++r){
        #pragma unroll
        for (int j = 0; j < 8; ++j) acc[r][j] = 0.f;
    }
    for (int d = 0; d < DH; ++d){
        float4 ka = *(const float4*)&Ktb[(size_t)d * SS + c0];
        float4 kb = *(const float4*)&Ktb[(size_t)d * SS + c0 + 4];
        float kv[8] = {ka.x, ka.y, ka.z, ka.w, kb.x, kb.y, kb.z, kb.w};
        float4 qa = *(const float4*)&qst[d][0];
        float4 qb = *(const float4*)&qst[d][4];
        float qv[8] = {qa.x, qa.y, qa.z, qa.w, qb.x, qb.y, qb.z, qb.w};
        #pragma unroll
        for (int r = 0; r < QT; ++r)
            #pragma unroll
            for (int j = 0; j < 8; ++j)
                acc[r][j] = fmaf(qv[r], kv[j], acc[r][j]);
    }

    // ---- scale (1/sqrt(D) * 1/temperature) + diagonal boost ----
    const float SCL = 0.15625f;       // 0.125 * 1.25
    #pragma unroll
    for (int r = 0; r < QT; ++r){
        const int trow = t0 + r;
        #pragma unroll
        for (int j = 0; j < 8; ++j){
            float v = acc[r][j] * SCL;
            if (c0 + j == trow) v *= 1.15f;   // 1 + ACH*0.3
            acc[r][j] = v;
        }
    }

    // ---- phase 2: exact top-k threshold (radix select, MSB->LSB bytes) ----
    unsigned prefix[QT];
    int kkr[QT];
    #pragma unroll
    for (int r = 0; r < QT; ++r){ prefix[r] = 0u; kkr[r] = KKSEL; }

    for (int pass = 3; pass >= 0; --pass){
        const int sh = pass * 8;
        for (int l = tid; l < QT * 257; l += 256) ((unsigned*)su.hist)[l] = 0u;
        __syncthreads();
        #pragma unroll
        for (int r = 0; r < QT; ++r){
            #pragma unroll
            for (int j = 0; j < 8; ++j){
                const unsigned key = sortkey(acc[r][j]);
                // bytes above current byte must match already-decided prefix
                const bool match = ((((key ^ prefix[r]) >> sh) >> 8) == 0u);
                if (match) atomicAdd(&su.hist[r][(key >> sh) & 255u], 1u);
            }
        }
        __syncthreads();
        // suffix-sum over 256 bins (all rows in parallel)
        for (int off = 1; off < 256; off <<= 1){
            unsigned v[QT];
            #pragma unroll
            for (int r = 0; r < QT; ++r){
                unsigned x = su.hist[r][tid];
                if (tid + off < 256) x += su.hist[r][tid + off];
                v[r] = x;
            }
            __syncthreads();
            #pragma unroll
            for (int r = 0; r < QT; ++r) su.hist[r][tid] = v[r];
            __syncthreads();
        }
        // pick the bin where cumulative(>=bin) first reaches kk_remaining
        #pragma unroll
        for (int r = 0; r < QT; ++r){
            const unsigned cum  = su.hist[r][tid];
            const unsigned cnxt = (tid < 255) ? su.hist[r][tid + 1] : 0u;
            const unsigned k = (unsigned)kkr[r];
            if (cum >= k && cnxt < k){ selbin[r] = (unsigned)tid; selkk[r] = k - cnxt; }
        }
        __syncthreads();
        #pragma unroll
        for (int r = 0; r < QT; ++r){
            prefix[r] |= (selbin[r] << sh);
            kkr[r] = (int)selkk[r];
        }
        __syncthreads();
    }
    // boost entries >= min_topk  (1 + (-DA)*0.3 = 1.15)
    #pragma unroll
    for (int r = 0; r < QT; ++r){
        #pragma unroll
        for (int j = 0; j < 8; ++j){
            if (sortkey(acc[r][j]) >= prefix[r]) acc[r][j] *= 1.15f;
        }
    }

    // ---- phase 3: softmax ----
    float mx[QT];
    #pragma unroll
    for (int r = 0; r < QT; ++r){
        float m = acc[r][0];
        #pragma unroll
        for (int j = 1; j < 8; ++j) m = fmaxf(m, acc[r][j]);
        #pragma unroll
        for (int off = 32; off >= 1; off >>= 1) m = fmaxf(m, __shfl_xor(m, off, 64));
        mx[r] = m;
    }
    if (lane == 0){
        #pragma unroll
        for (int r = 0; r < QT; ++r) redw[r][wave] = mx[r];
    }
    __syncthreads();
    #pragma unroll
    for (int r = 0; r < QT; ++r)
        mx[r] = fmaxf(fmaxf(redw[r][0], redw[r][1]), fmaxf(redw[r][2], redw[r][3]));
    __syncthreads();   // before redw reuse

    float sm[QT];
    #pragma unroll
    for (int r = 0; r < QT; ++r){
        float s = 0.f;
        #pragma unroll
        for (int j = 0; j < 8; ++j){
            const float e = __expf(acc[r][j] - mx[r]);
            acc[r][j] = e;
            s += e;
        }
        #pragma unroll
        for (int off = 32; off >= 1; off >>= 1) s += __shfl_xor(s, off, 64);
        sm[r] = s;
    }
    if (lane == 0){
        #pragma unroll
        for (int r = 0; r < QT; ++r) redw[r][wave] = sm[r];
    }
    __syncthreads();
    #pragma unroll
    for (int r = 0; r < QT; ++r){
        const float tot = redw[r][0] + redw[r][1] + redw[r][2] + redw[r][3];
        const float inv = 1.f / tot;
        #pragma unroll
        for (int j = 0; j < 8; ++j)
            probs[r][c0 + j] = __float2bfloat16(acc[r][j] * inv);
    }
    __syncthreads();

    // ---- phase 4: O = P @ V   (c-range split across the 4 waves) ----
    float o[QT];
    #pragma unroll
    for (int r = 0; r < QT; ++r) o[r] = 0.f;
    const int cbeg = wave * (SS / 4);
    for (int c = cbeg; c < cbeg + (SS / 4); c += 4){
        const float v0 = Vb[(size_t)(c + 0) * DH + lane];
        const float v1 = Vb[(size_t)(c + 1) * DH + lane];
        const float v2 = Vb[(size_t)(c + 2) * DH + lane];
        const float v3 = Vb[(size_t)(c + 3) * DH + lane];
        #pragma unroll
        for (int r = 0; r < QT; ++r){
            const uint2 pp = *(const uint2*)&probs[r][c];
            const float p0 = __uint_as_float(pp.x << 16);
            const float p1 = __uint_as_float(pp.x & 0xFFFF0000u);
            const float p2 = __uint_as_float(pp.y << 16);
            const float p3 = __uint_as_float(pp.y & 0xFFFF0000u);
            o[r] += p0 * v0 + p1 * v1 + p2 * v2 + p3 * v3;
        }
    }
    #pragma unroll
    for (int r = 0; r < QT; ++r) su.red2[wave][r][lane] = o[r];
    __syncthreads();
    const int b = bh >> 4, h = bh & 15;
    for (int idx = tid; idx < QT * DH; idx += 256){
        const int r = idx >> 6, dd = idx & 63;
        const float s = su.red2[0][r][dd] + su.red2[1][r][dd]
                      + su.red2[2][r][dd] + su.red2[3][r][dd];
        AO[((size_t)b * SS + (t0 + r)) * EE + h * DH + dd] = s;   // [b][s][e]
    }
}

// ---------------------------------------------------------------------------
extern "C" void kernel_launch(void* const* d_in, const int* in_sizes, int n_in,
                              void* d_out, int out_size, void* d_ws, size_t ws_size,
                              hipStream_t stream)
{
    const float* query = (const float*)d_in[0];
    const float* key   = (const float*)d_in[1];
    const float* value = (const float*)d_in[2];
    const float* Wq    = (const float*)d_in[3];
    const float* bq    = (const float*)d_in[4];
    const float* Wk    = (const float*)d_in[5];
    const float* bk    = (const float*)d_in[6];
    const float* Wv    = (const float*)d_in[7];
    const float* bv    = (const float*)d_in[8];
    const float* Wo    = (const float*)d_in[9];
    const float* bo    = (const float*)d_in[10];
    const float* ts    = (const float*)d_in[11];
    float* out = (float*)d_out;
    float* ws  = (float*)d_ws;

    const size_t NE = (size_t)BB * HH * SS * DH;   // 4M floats per buffer
    float* Qw  = ws;             // [bh][s][d]
    float* Ktw = ws + NE;        // [bh][d][s]
    float* Vw  = ws + 2 * NE;    // [bh][s][d]
    float* AOw = ws + 3 * NE;    // [b][s][e]   (needs 64 MB of ws total)

    dim3 gg(EE / 64, (BB * SS) / 64), bb(256);
    hipLaunchKernelGGL((gemm_proj<0>), gg, bb, 0, stream, query, Wq, bq, nullptr, Qw);
    hipLaunchKernelGGL((gemm_proj<1>), gg, bb, 0, stream, key,   Wk, bk, ts,      Ktw);
    hipLaunchKernelGGL((gemm_proj<2>), gg, bb, 0, stream, value, Wv, bv, nullptr, Vw);
    hipLaunchKernelGGL(attn_kernel, dim3(BB * HH * (SS / QT)), dim3(256), 0, stream,
                       Qw, Ktw, Vw, AOw);
    hipLaunchKernelGGL((gemm_proj<3>), gg, bb, 0, stream, AOw, Wo, bo, nullptr, out);
}

// Round 2
// 1293.998 us; speedup vs baseline: 1.3646x; 1.3646x over previous
//
#include <hip/hip_runtime.h>
#include <cstdint>
#include <cstddef>

#define BB 2
#define SS 2048
#define EE 1024
#define HH 16
#define DH 64
#define KKSEL 409   // kk = int(2048*0.2)
#define QT 16       // query rows per attention block

typedef __attribute__((ext_vector_type(8))) short bf16x8;
typedef __attribute__((ext_vector_type(4))) float f32x4;

__device__ __forceinline__ unsigned short f2bf(float f){
    unsigned u = __float_as_uint(f);
    u += 0x7fffu + ((u >> 16) & 1u);          // RNE
    return (unsigned short)(u >> 16);
}
__device__ __forceinline__ float bf2f(unsigned short h){
    return __uint_as_float(((unsigned)h) << 16);
}
__device__ __forceinline__ unsigned sortkey(float f){
    unsigned u = __float_as_uint(f);
    return (u & 0x80000000u) ? ~u : (u | 0x80000000u);
}
__device__ __forceinline__ float inv_sortkey(unsigned k){
    unsigned u = (k & 0x80000000u) ? (k & 0x7fffffffu) : ~k;
    return __uint_as_float(u);
}

// ---------------------------------------------------------------------------
// Projection GEMM: C = X(4096x1024) @ W(1024x1024) + bias
// MODE 0: Q fp32 [bh][s][d]
// MODE 1: K bf16 hi/lo [bh][s][d], scaled by time_scales[h]
// MODE 2: V^T bf16 hi/lo [bh][d][s]
// MODE 3: plain fp32 row-major (final projection -> d_out)
// ---------------------------------------------------------------------------
template<int MODE>
__global__ __launch_bounds__(256) void gemm_proj(const float* __restrict__ X,
                                                 const float* __restrict__ W,
                                                 const float* __restrict__ bias,
                                                 const float* __restrict__ ts,
                                                 float* __restrict__ OutF,
                                                 unsigned short* __restrict__ OutH,
                                                 unsigned short* __restrict__ OutL)
{
    __shared__ float As[16][68];
    __shared__ float Bs[16][64];
    const int tid = threadIdx.x;
    const int m0 = blockIdx.y * 64;
    const int n0 = blockIdx.x * 64;
    const int ty = tid >> 4, tx = tid & 15;
    const int am = tid >> 2, ak = (tid & 3) * 4;
    const int bk = tid >> 4, bn = (tid & 15) * 4;
    float acc[4][4] = {};

    for (int k0 = 0; k0 < EE; k0 += 16){
        float4 av = *(const float4*)&X[(size_t)(m0 + am) * EE + k0 + ak];
        As[ak + 0][am] = av.x; As[ak + 1][am] = av.y;
        As[ak + 2][am] = av.z; As[ak + 3][am] = av.w;
        *(float4*)&Bs[bk][bn] = *(const float4*)&W[(size_t)(k0 + bk) * EE + n0 + bn];
        __syncthreads();
        #pragma unroll
        for (int k = 0; k < 16; ++k){
            float4 fa = *(const float4*)&As[k][ty * 4];
            float4 fb = *(const float4*)&Bs[k][tx * 4];
            float a[4] = {fa.x, fa.y, fa.z, fa.w};
            float b[4] = {fb.x, fb.y, fb.z, fb.w};
            #pragma unroll
            for (int i = 0; i < 4; ++i)
                #pragma unroll
                for (int j = 0; j < 4; ++j)
                    acc[i][j] = fmaf(a[i], b[j], acc[i][j]);
        }
        __syncthreads();
    }

    const int h = n0 >> 6;              // head (n0 is a multiple of 64)
    if (MODE == 3){
        #pragma unroll
        for (int i = 0; i < 4; ++i){
            const int m = m0 + ty * 4 + i;
            float4 o;
            o.x = acc[i][0] + bias[n0 + tx*4 + 0];
            o.y = acc[i][1] + bias[n0 + tx*4 + 1];
            o.z = acc[i][2] + bias[n0 + tx*4 + 2];
            o.w = acc[i][3] + bias[n0 + tx*4 + 3];
            *(float4*)&OutF[(size_t)m * EE + n0 + tx*4] = o;
        }
    } else if (MODE == 0){
        #pragma unroll
        for (int i = 0; i < 4; ++i){
            const int m = m0 + ty * 4 + i;
            const int b = m >> 11, s = m & (SS - 1);
            float4 o;
            o.x = acc[i][0] + bias[n0 + tx*4 + 0];
            o.y = acc[i][1] + bias[n0 + tx*4 + 1];
            o.z = acc[i][2] + bias[n0 + tx*4 + 2];
            o.w = acc[i][3] + bias[n0 + tx*4 + 3];
            *(float4*)&OutF[(((size_t)(b * HH + h)) * SS + s) * DH + tx*4] = o;
        }
    } else if (MODE == 1){
        const float tsc = ts[h];
        #pragma unroll
        for (int i = 0; i < 4; ++i){
            const int m = m0 + ty * 4 + i;
            const int b = m >> 11, s = m & (SS - 1);
            ushort4 hi, lo;
            unsigned short* hp = &hi.x; unsigned short* lp = &lo.x;
            #pragma unroll
            for (int j = 0; j < 4; ++j){
                float v = (acc[i][j] + bias[n0 + tx*4 + j]) * tsc;
                unsigned short hh = f2bf(v);
                hp[j] = hh;
                lp[j] = f2bf(v - bf2f(hh));
            }
            *(ushort4*)&OutH[(((size_t)(b * HH + h)) * SS + s) * DH + tx*4] = hi;
            *(ushort4*)&OutL[(((size_t)(b * HH + h)) * SS + s) * DH + tx*4] = lo;
        }
    } else { // MODE 2: V^T
        const int b = m0 >> 11;
        const int s0 = (m0 & (SS - 1)) + ty * 4;
        #pragma unroll
        for (int j = 0; j < 4; ++j){
            const int d = tx*4 + j;
            ushort4 hi, lo;
            unsigned short* hp = &hi.x; unsigned short* lp = &lo.x;
            #pragma unroll
            for (int i = 0; i < 4; ++i){
                float v = acc[i][j] + bias[n0 + d];
                unsigned short hh = f2bf(v);
                hp[i] = hh;
                lp[i] = f2bf(v - bf2f(hh));
            }
            *(ushort4*)&OutH[(((size_t)(b * HH + h)) * DH + d) * SS + s0] = hi;
            *(ushort4*)&OutL[(((size_t)(b * HH + h)) * DH + d) * SS + s0] = lo;
        }
    }
}

// ---------------------------------------------------------------------------
// Fused attention, MFMA edition. One block = 16 query rows of one (b,h).
// Wave w owns score cols [w*512, w*512+512) as 32 C-fragments (128 VGPRs).
// C/D layout: col = lane&15, row = (lane>>4)*4 + reg   [m89/m91 verified]
// A layout:   m  = lane&15, k  = (lane>>4)*8 + j       [m118/m120]
// ---------------------------------------------------------------------------
#define PSTRIDE 264   // probs LDS row stride (bf16 elems), padded vs 256

__global__ __launch_bounds__(256, 2) void attn_kernel(
        const float* __restrict__ Q,
        const unsigned short* __restrict__ Khi, const unsigned short* __restrict__ Klo,
        const unsigned short* __restrict__ Vthi, const unsigned short* __restrict__ Vtlo,
        float* __restrict__ AO)
{
    __shared__ __align__(16) unsigned short probs[4 * QT * PSTRIDE];  // 33792 B
    __shared__ __align__(16) unsigned histred[4160];  // hist 16x256 u32 | red 4x16x65 f32
    __shared__ float wsums[4][16];
    __shared__ unsigned prefcur[16];
    __shared__ int kkcur[16];

    const int tid  = threadIdx.x;
    const int lane = tid & 63;
    const int wave = tid >> 6;
    const int qd   = lane >> 4;     // quad 0..3
    const int c16  = lane & 15;
    const int bh   = blockIdx.x >> 7;          // 128 tiles per (b,h)
    const int t0   = (blockIdx.x & 127) * QT;
    const int wbase = wave * 512;

    if (tid < 16){ prefcur[tid] = 0u; kkcur[tid] = KKSEL; }

    // ---- Q fragments (split hi/lo) for rows t0..t0+15 ----
    bf16x8 qh[2], ql[2];
    {
        const float* qrow = Q + ((size_t)bh * SS + t0 + c16) * DH + qd * 8;
        #pragma unroll
        for (int kc = 0; kc < 2; ++kc){
            float4 f0 = *(const float4*)(qrow + kc*32);
            float4 f1 = *(const float4*)(qrow + kc*32 + 4);
            float f[8] = {f0.x,f0.y,f0.z,f0.w,f1.x,f1.y,f1.z,f1.w};
            #pragma unroll
            for (int j = 0; j < 8; ++j){
                unsigned short hh = f2bf(f[j]);
                qh[kc][j] = (short)hh;
                ql[kc][j] = (short)f2bf(f[j] - bf2f(hh));
            }
        }
    }

    // ---- phase 1: scores via split-bf16 MFMA ----
    f32x4 acc[32];
    const unsigned short* Kh = Khi + (size_t)bh * SS * DH;
    const unsigned short* Kl = Klo + (size_t)bh * SS * DH;
    #pragma unroll
    for (int t = 0; t < 32; ++t){
        f32x4 a = {0.f, 0.f, 0.f, 0.f};
        const int srow = wbase + t*16 + c16;
        const unsigned short* kp = Kh + (size_t)srow * DH + qd*8;
        const unsigned short* lp = Kl + (size_t)srow * DH + qd*8;
        #pragma unroll
        for (int kc = 0; kc < 2; ++kc){
            bf16x8 kh = *(const bf16x8*)(kp + kc*32);
            bf16x8 kl = *(const bf16x8*)(lp + kc*32);
            a = __builtin_amdgcn_mfma_f32_16x16x32_bf16(qh[kc], kh, a, 0, 0, 0);
            a = __builtin_amdgcn_mfma_f32_16x16x32_bf16(ql[kc], kh, a, 0, 0, 0);
            a = __builtin_amdgcn_mfma_f32_16x16x32_bf16(qh[kc], kl, a, 0, 0, 0);
        }
        acc[t] = a;
    }

    // ---- scale + diag boost, convert to sortkeys in place ----
    #pragma unroll
    for (int t = 0; t < 32; ++t){
        const int colg = wbase + t*16 + c16;
        #pragma unroll
        for (int r = 0; r < 4; ++r){
            float v = acc[t][r] * 0.15625f;        // 1/8 * 1.25
            if (colg == t0 + qd*4 + r) v *= 1.15f; // diagonal
            acc[t][r] = __uint_as_float(sortkey(v));
        }
    }
    __syncthreads();   // prefcur/kkcur init visible; enter select

    // ---- phase 2: exact top-k threshold (radix select over registers) ----
    unsigned* hist = histred;   // 16 rows x 256 bins
    for (int pass = 3; pass >= 0; --pass){
        const int sh = pass * 8;
        #pragma unroll
        for (int i = 0; i < 16; ++i) hist[tid + i*256] = 0u;
        unsigned pref[4];
        #pragma unroll
        for (int r = 0; r < 4; ++r) pref[r] = prefcur[qd*4 + r];
        __syncthreads();
        #pragma unroll
        for (int t = 0; t < 32; ++t){
            #pragma unroll
            for (int r = 0; r < 4; ++r){
                const unsigned key = __float_as_uint(acc[t][r]);
                if ((((key ^ pref[r]) >> sh) >> 8) == 0u)
                    atomicAdd(&hist[(qd*4 + r)*256 + ((key >> sh) & 255u)], 1u);
            }
        }
        __syncthreads();
        // wave w scans rows 4w..4w+3; lane covers 4 bins/row; suffix-scan via shfl
        #pragma unroll
        for (int rr = 0; rr < 4; ++rr){
            const int r = wave*4 + rr;
            uint4 b = *(const uint4*)&hist[r*256 + lane*4];
            const unsigned own = b.x + b.y + b.z + b.w;
            unsigned S = own;
            #pragma unroll
            for (int off = 1; off < 64; off <<= 1){
                unsigned tmp = __shfl(S, lane + off, 64);
                if (lane + off > 63) tmp = 0u;
                S += tmp;
            }
            const unsigned ku = (unsigned)kkcur[r];
            const unsigned cum0 = S;
            const unsigned cum1 = cum0 - b.x;
            const unsigned cum2 = cum1 - b.y;
            const unsigned cum3 = cum2 - b.z;
            const unsigned cum4 = cum3 - b.w;
            int j = -1; unsigned cn = 0;
            if      (cum0 >= ku && cum1 < ku){ j = 0; cn = cum1; }
            else if (cum1 >= ku && cum2 < ku){ j = 1; cn = cum2; }
            else if (cum2 >= ku && cum3 < ku){ j = 2; cn = cum3; }
            else if (cum3 >= ku && cum4 < ku){ j = 3; cn = cum4; }
            if (j >= 0){
                prefcur[r] |= (unsigned)(lane*4 + j) << sh;
                kkcur[r] = (int)(ku - cn);
            }
        }
        __syncthreads();
    }

    // ---- phase 3: boost + exp + row sums (no max-subtract; scores bounded) ----
    unsigned thr[4];
    #pragma unroll
    for (int r = 0; r < 4; ++r) thr[r] = prefcur[qd*4 + r];
    float psum[4] = {0.f, 0.f, 0.f, 0.f};
    #pragma unroll
    for (int t = 0; t < 32; ++t){
        #pragma unroll
        for (int r = 0; r < 4; ++r){
            const unsigned key = __float_as_uint(acc[t][r]);
            float s = inv_sortkey(key);
            s *= (key >= thr[r]) ? 1.15f : 1.0f;
            const float e = __expf(s);
            acc[t][r] = e;
            psum[r] += e;
        }
    }
    #pragma unroll
    for (int off = 1; off <= 8; off <<= 1){
        #pragma unroll
        for (int r = 0; r < 4; ++r) psum[r] += __shfl_xor(psum[r], off, 64);
    }
    if (c16 == 0){
        #pragma unroll
        for (int r = 0; r < 4; ++r) wsums[wave][qd*4 + r] = psum[r];
    }
    __syncthreads();
    float pinv[4];
    #pragma unroll
    for (int r = 0; r < 4; ++r){
        const int row = qd*4 + r;
        pinv[r] = 1.f / (wsums[0][row] + wsums[1][row] + wsums[2][row] + wsums[3][row]);
    }

    // ---- phase 4: O = P @ V via MFMA (P -> LDS bf16 -> A-frags; V^T split) ----
    const unsigned short* Vh = Vthi + (size_t)bh * DH * SS;
    const unsigned short* Vl = Vtlo + (size_t)bh * DH * SS;
    unsigned short* pw = probs + wave * (QT * PSTRIDE);
    f32x4 oacc[4];
    #pragma unroll
    for (int dt = 0; dt < 4; ++dt) oacc[dt] = (f32x4){0.f, 0.f, 0.f, 0.f};

    #pragma unroll
    for (int half = 0; half < 2; ++half){
        #pragma unroll
        for (int tt = 0; tt < 16; ++tt){
            const int t = half*16 + tt;
            #pragma unroll
            for (int r = 0; r < 4; ++r)
                pw[(qd*4 + r) * PSTRIDE + tt*16 + c16] = f2bf(acc[t][r] * pinv[r]);
        }
        // per-wave region: same-wave ds_write->ds_read, compiler inserts lgkm waits
        #pragma unroll
        for (int kc = 0; kc < 8; ++kc){
            bf16x8 pf = *(const bf16x8*)&pw[c16 * PSTRIDE + kc*32 + qd*8];
            const int sbase = wbase + half*256 + kc*32 + qd*8;
            #pragma unroll
            for (int dt = 0; dt < 4; ++dt){
                const int d = dt*16 + c16;
                bf16x8 vh = *(const bf16x8*)(Vh + (size_t)d * SS + sbase);
                bf16x8 vl = *(const bf16x8*)(Vl + (size_t)d * SS + sbase);
                oacc[dt] = __builtin_amdgcn_mfma_f32_16x16x32_bf16(pf, vh, oacc[dt], 0, 0, 0);
                oacc[dt] = __builtin_amdgcn_mfma_f32_16x16x32_bf16(pf, vl, oacc[dt], 0, 0, 0);
            }
        }
    }

    // ---- cross-wave O reduction + store ----
    float* red = (float*)histred;   // 4 x 16 x 65
    #pragma unroll
    for (int dt = 0; dt < 4; ++dt)
        #pragma unroll
        for (int r = 0; r < 4; ++r)
            red[(wave*16 + qd*4 + r) * 65 + dt*16 + c16] = oacc[dt][r];
    __syncthreads();

    const int b = bh >> 4, h = bh & 15;
    {
        const int r  = tid >> 4;
        const int c4 = (tid & 15) * 4;
        float4 o;
        float* op = &o.x;
        #pragma unroll
        for (int j = 0; j < 4; ++j){
            float s = 0.f;
            #pragma unroll
            for (int w = 0; w < 4; ++w) s += red[(w*16 + r) * 65 + c4 + j];
            op[j] = s;
        }
        *(float4*)&AO[((size_t)b * SS + t0 + r) * EE + h*DH + c4] = o;
    }
}

// ---------------------------------------------------------------------------
extern "C" void kernel_launch(void* const* d_in, const int* in_sizes, int n_in,
                              void* d_out, int out_size, void* d_ws, size_t ws_size,
                              hipStream_t stream)
{
    const float* query = (const float*)d_in[0];
    const float* key   = (const float*)d_in[1];
    const float* value = (const float*)d_in[2];
    const float* Wq    = (const float*)d_in[3];
    const float* bq    = (const float*)d_in[4];
    const float* Wk    = (const float*)d_in[5];
    const float* bk    = (const float*)d_in[6];
    const float* Wv    = (const float*)d_in[7];
    const float* bv    = (const float*)d_in[8];
    const float* Wo    = (const float*)d_in[9];
    const float* bo    = (const float*)d_in[10];
    const float* ts    = (const float*)d_in[11];
    float* out = (float*)d_out;
    float* ws  = (float*)d_ws;

    const size_t NE = (size_t)BB * HH * SS * DH;          // 4M elems
    float*          Qw   = ws;                            // 16 MB fp32
    unsigned short* Khi  = (unsigned short*)(ws + NE);    // 8 MB bf16
    unsigned short* Klo  = Khi + NE;                      // 8 MB
    unsigned short* Vthi = Klo + NE;                      // 8 MB
    unsigned short* Vtlo = Vthi + NE;                     // 8 MB
    float*          AOw  = (float*)(Vtlo + NE);           // 16 MB

    dim3 gg(EE / 64, (BB * SS) / 64), bb(256);
    hipLaunchKernelGGL((gemm_proj<0>), gg, bb, 0, stream, query, Wq, bq, nullptr, Qw, nullptr, nullptr);
    hipLaunchKernelGGL((gemm_proj<1>), gg, bb, 0, stream, key,   Wk, bk, ts, nullptr, Khi, Klo);
    hipLaunchKernelGGL((gemm_proj<2>), gg, bb, 0, stream, value, Wv, bv, nullptr, nullptr, Vthi, Vtlo);
    hipLaunchKernelGGL(attn_kernel, dim3(BB * HH * (SS / QT)), dim3(256), 0, stream,
                       Qw, Khi, Klo, Vthi, Vtlo, AOw);
    hipLaunchKernelGGL((gemm_proj<3>), gg, bb, 0, stream, AOw, Wo, bo, nullptr, out, nullptr, nullptr);
}

// Round 3
// 957.384 us; speedup vs baseline: 1.8443x; 1.3516x over previous
//
#include <hip/hip_runtime.h>
#include <cstdint>
#include <cstddef>

#define BB 2
#define SS 2048
#define EE 1024
#define HH 16
#define DH 64
#define KKSEL 409   // kk = int(2048*0.2)
#define QT 16       // query rows per attention block

typedef __attribute__((ext_vector_type(8))) short bf16x8;
typedef __attribute__((ext_vector_type(4))) float f32x4;
typedef unsigned short ushort_t;

__device__ __forceinline__ unsigned short f2bf(float f){
    unsigned u = __float_as_uint(f);
    u += 0x7fffu + ((u >> 16) & 1u);          // RNE
    return (unsigned short)(u >> 16);
}
__device__ __forceinline__ float bf2f(unsigned short h){
    return __uint_as_float(((unsigned)h) << 16);
}
__device__ __forceinline__ unsigned sortkey(float f){
    unsigned u = __float_as_uint(f);
    return (u & 0x80000000u) ? ~u : (u | 0x80000000u);
}
__device__ __forceinline__ float inv_sortkey(unsigned k){
    unsigned u = (k & 0x80000000u) ? (k & 0x7fffffffu) : ~k;
    return __uint_as_float(u);
}

// ---------------------------------------------------------------------------
// convert_x: fp32 (4096x1024 flat) -> bf16 hi + lo, same layout
// ---------------------------------------------------------------------------
__global__ __launch_bounds__(256) void convert_x(const float* __restrict__ X,
                                                 ushort_t* __restrict__ H,
                                                 ushort_t* __restrict__ L)
{
    const int i = (blockIdx.x * 256 + threadIdx.x) * 4;
    float4 v = *(const float4*)&X[i];
    const float f[4] = {v.x, v.y, v.z, v.w};
    ushort4 h, l;
    ushort_t* hp = &h.x; ushort_t* lp = &l.x;
    #pragma unroll
    for (int j = 0; j < 4; ++j){
        ushort_t hh = f2bf(f[j]);
        hp[j] = hh;
        lp[j] = f2bf(f[j] - bf2f(hh));
    }
    *(ushort4*)&H[i] = h;
    *(ushort4*)&L[i] = l;
}

// ---------------------------------------------------------------------------
// convert_wt: W (1024x1024 [k][n]) -> W^T bf16 hi/lo ([n][k])
// ---------------------------------------------------------------------------
__global__ __launch_bounds__(256) void convert_wt(const float* __restrict__ W,
                                                  ushort_t* __restrict__ Ht,
                                                  ushort_t* __restrict__ Lt)
{
    __shared__ float T[64][65];
    const int tid = threadIdx.x;
    const int ty = tid >> 4, tx = tid & 15;
    const int n0 = blockIdx.x * 64, k0 = blockIdx.y * 64;
    #pragma unroll
    for (int i = 0; i < 4; ++i){
        const int kl = ty + i * 16;
        float4 w = *(const float4*)&W[(size_t)(k0 + kl) * EE + n0 + tx * 4];
        T[kl][tx*4 + 0] = w.x; T[kl][tx*4 + 1] = w.y;
        T[kl][tx*4 + 2] = w.z; T[kl][tx*4 + 3] = w.w;
    }
    __syncthreads();
    #pragma unroll
    for (int i = 0; i < 4; ++i){
        const int nl = ty + i * 16;
        ushort4 h, l;
        ushort_t* hp = &h.x; ushort_t* lp = &l.x;
        #pragma unroll
        for (int j = 0; j < 4; ++j){
            const float v = T[tx*4 + j][nl];
            ushort_t hh = f2bf(v);
            hp[j] = hh;
            lp[j] = f2bf(v - bf2f(hh));
        }
        const size_t o = (size_t)(n0 + nl) * EE + k0 + tx * 4;
        *(ushort4*)&Ht[o] = h;
        *(ushort4*)&Lt[o] = l;
    }
}

// ---------------------------------------------------------------------------
// Split-bf16 MFMA GEMM: C = X(4096x1024) @ W(1024x1024) + bias
// X given as hi/lo bf16 [m][k]; W given as transposed hi/lo bf16 [n][k].
// acc = Xh*Wh + Xh*Wl + Xl*Wh  (fp32 accum; Xl*Wl term ~2^-18, dropped)
// MODE 0: Q  -> bf16 hi/lo [bh][s][d]
// MODE 1: K  -> bf16 hi/lo [bh][s][d], scaled by ts[h]
// MODE 2: V  -> bf16 hi only, transposed [bh][d][s]
// MODE 3: fp32 row-major (final projection -> d_out)
// 128x128 tile, 4 waves (each 64x64), BK=32, LDS double-buffered (1 block/CU).
// Orientation: MODE!=2 puts W first (n lands in regs -> vectorized d stores);
// MODE 2 puts X first (s lands in regs -> vectorized V^T stores).
// ---------------------------------------------------------------------------
template<int MODE>
__global__ __launch_bounds__(256) void gemm_mfma(
        const ushort_t* __restrict__ Xh, const ushort_t* __restrict__ Xl,
        const ushort_t* __restrict__ Wth, const ushort_t* __restrict__ Wtl,
        const float* __restrict__ bias, const float* __restrict__ ts,
        float* __restrict__ OutF, ushort_t* __restrict__ OutH,
        ushort_t* __restrict__ OutL)
{
    __shared__ ushort_t buf[2][16384];   // [stage][Ah|Al|Bh|Bl], 32 KB each
    const int tid  = threadIdx.x;
    const int lane = tid & 63, wave = tid >> 6;
    const int c16  = lane & 15, qd = lane >> 4;
    const int m0 = blockIdx.y * 128, n0 = blockIdx.x * 128;
    const int wm = (wave >> 1) * 64, wn = (wave & 1) * 64;
    const int lrow = tid >> 1, lkg = (tid & 1) * 16;

    f32x4 acc[4][4];
    #pragma unroll
    for (int a = 0; a < 4; ++a)
        #pragma unroll
        for (int b = 0; b < 4; ++b) acc[a][b] = (f32x4){0.f,0.f,0.f,0.f};

    // prologue: stage k0 = 0 into buf[0]
    {
        const size_t xo = (size_t)(m0 + lrow) * EE + lkg;
        const size_t wo = (size_t)(n0 + lrow) * EE + lkg;
        bf16x8 x0 = *(const bf16x8*)&Xh[xo];
        bf16x8 x1 = *(const bf16x8*)&Xh[xo + 8];
        bf16x8 x2 = *(const bf16x8*)&Xl[xo];
        bf16x8 x3 = *(const bf16x8*)&Xl[xo + 8];
        bf16x8 w0 = *(const bf16x8*)&Wth[wo];
        bf16x8 w1 = *(const bf16x8*)&Wth[wo + 8];
        bf16x8 w2 = *(const bf16x8*)&Wtl[wo];
        bf16x8 w3 = *(const bf16x8*)&Wtl[wo + 8];
        *(bf16x8*)&buf[0][lrow*32 + lkg]          = x0;
        *(bf16x8*)&buf[0][lrow*32 + lkg + 8]      = x1;
        *(bf16x8*)&buf[0][4096 + lrow*32 + lkg]   = x2;
        *(bf16x8*)&buf[0][4096 + lrow*32 + lkg+8] = x3;
        *(bf16x8*)&buf[0][8192 + lrow*32 + lkg]   = w0;
        *(bf16x8*)&buf[0][8192 + lrow*32 + lkg+8] = w1;
        *(bf16x8*)&buf[0][12288 + lrow*32 + lkg]  = w2;
        *(bf16x8*)&buf[0][12288 + lrow*32 + lkg+8]= w3;
    }
    __syncthreads();

    int cur = 0;
    for (int k0 = 0; k0 < EE; k0 += 32){
        const bool more = (k0 + 32) < EE;
        bf16x8 g[8];
        if (more){
            const size_t xo = (size_t)(m0 + lrow) * EE + k0 + 32 + lkg;
            const size_t wo = (size_t)(n0 + lrow) * EE + k0 + 32 + lkg;
            g[0] = *(const bf16x8*)&Xh[xo];  g[1] = *(const bf16x8*)&Xh[xo + 8];
            g[2] = *(const bf16x8*)&Xl[xo];  g[3] = *(const bf16x8*)&Xl[xo + 8];
            g[4] = *(const bf16x8*)&Wth[wo]; g[5] = *(const bf16x8*)&Wth[wo + 8];
            g[6] = *(const bf16x8*)&Wtl[wo]; g[7] = *(const bf16x8*)&Wtl[wo + 8];
        }
        const ushort_t* A0 = &buf[cur][0];
        const ushort_t* A1 = &buf[cur][4096];
        const ushort_t* B0 = &buf[cur][8192];
        const ushort_t* B1 = &buf[cur][12288];
        bf16x8 afh[4], afl[4], bfh[4], bfl[4];
        #pragma unroll
        for (int i = 0; i < 4; ++i){
            afh[i] = *(const bf16x8*)&A0[(wm + i*16 + c16)*32 + qd*8];
            afl[i] = *(const bf16x8*)&A1[(wm + i*16 + c16)*32 + qd*8];
            bfh[i] = *(const bf16x8*)&B0[(wn + i*16 + c16)*32 + qd*8];
            bfl[i] = *(const bf16x8*)&B1[(wn + i*16 + c16)*32 + qd*8];
        }
        #pragma unroll
        for (int a = 0; a < 4; ++a){
            #pragma unroll
            for (int b = 0; b < 4; ++b){
                if (MODE == 2){   // X first: D rows <- s, cols <- d
                    acc[a][b] = __builtin_amdgcn_mfma_f32_16x16x32_bf16(afh[a], bfh[b], acc[a][b], 0,0,0);
                    acc[a][b] = __builtin_amdgcn_mfma_f32_16x16x32_bf16(afh[a], bfl[b], acc[a][b], 0,0,0);
                    acc[a][b] = __builtin_amdgcn_mfma_f32_16x16x32_bf16(afl[a], bfh[b], acc[a][b], 0,0,0);
                } else {          // W first: D rows <- n, cols <- m
                    acc[a][b] = __builtin_amdgcn_mfma_f32_16x16x32_bf16(bfh[a], afh[b], acc[a][b], 0,0,0);
                    acc[a][b] = __builtin_amdgcn_mfma_f32_16x16x32_bf16(bfh[a], afl[b], acc[a][b], 0,0,0);
                    acc[a][b] = __builtin_amdgcn_mfma_f32_16x16x32_bf16(bfl[a], afh[b], acc[a][b], 0,0,0);
                }
            }
        }
        if (more){
            ushort_t* N = &buf[cur ^ 1][0];
            *(bf16x8*)&N[lrow*32 + lkg]           = g[0];
            *(bf16x8*)&N[lrow*32 + lkg + 8]       = g[1];
            *(bf16x8*)&N[4096 + lrow*32 + lkg]    = g[2];
            *(bf16x8*)&N[4096 + lrow*32 + lkg+8]  = g[3];
            *(bf16x8*)&N[8192 + lrow*32 + lkg]    = g[4];
            *(bf16x8*)&N[8192 + lrow*32 + lkg+8]  = g[5];
            *(bf16x8*)&N[12288 + lrow*32 + lkg]   = g[6];
            *(bf16x8*)&N[12288 + lrow*32 + lkg+8] = g[7];
            __syncthreads();
            cur ^= 1;
        }
    }

    // ---- epilogue ----
    if (MODE == 3){
        #pragma unroll
        for (int a = 0; a < 4; ++a){
            const int ng = n0 + wn + a*16 + qd*4;
            float4 b4 = *(const float4*)&bias[ng];
            const float bb[4] = {b4.x, b4.y, b4.z, b4.w};
            #pragma unroll
            for (int b = 0; b < 4; ++b){
                const int mg = m0 + wm + b*16 + c16;
                float4 o;
                o.x = acc[a][b][0] + bb[0]; o.y = acc[a][b][1] + bb[1];
                o.z = acc[a][b][2] + bb[2]; o.w = acc[a][b][3] + bb[3];
                *(float4*)&OutF[(size_t)mg * EE + ng] = o;
            }
        }
    } else if (MODE == 0 || MODE == 1){
        #pragma unroll
        for (int a = 0; a < 4; ++a){
            const int ng = n0 + wn + a*16 + qd*4;
            const int h = ng >> 6, d0 = ng & 63;
            const float tsc = (MODE == 1) ? ts[h] : 1.0f;
            float4 b4 = *(const float4*)&bias[ng];
            const float bb[4] = {b4.x, b4.y, b4.z, b4.w};
            #pragma unroll
            for (int b = 0; b < 4; ++b){
                const int mg = m0 + wm + b*16 + c16;
                const int bi = mg >> 11, s = mg & (SS - 1);
                ushort4 hv, lv;
                ushort_t* hp = &hv.x; ushort_t* lp = &lv.x;
                #pragma unroll
                for (int r = 0; r < 4; ++r){
                    const float v = (acc[a][b][r] + bb[r]) * tsc;
                    ushort_t hh = f2bf(v);
                    hp[r] = hh;
                    lp[r] = f2bf(v - bf2f(hh));
                }
                const size_t o = (((size_t)(bi * HH + h)) * SS + s) * DH + d0;
                *(ushort4*)&OutH[o] = hv;
                *(ushort4*)&OutL[o] = lv;
            }
        }
    } else { // MODE 2: V^T hi only
        #pragma unroll
        for (int a = 0; a < 4; ++a){
            const int mg = m0 + wm + a*16 + qd*4;
            const int bi = mg >> 11, s0 = mg & (SS - 1);
            #pragma unroll
            for (int b = 0; b < 4; ++b){
                const int ng = n0 + wn + b*16 + c16;
                const int h = ng >> 6, d = ng & 63;
                const float bv = bias[ng];
                ushort4 hv;
                ushort_t* hp = &hv.x;
                #pragma unroll
                for (int r = 0; r < 4; ++r) hp[r] = f2bf(acc[a][b][r] + bv);
                *(ushort4*)&OutH[(((size_t)(bi * HH + h)) * DH + d) * SS + s0] = hv;
            }
        }
    }
}

// ---------------------------------------------------------------------------
// Fused attention (MFMA). One block = 16 query rows of one (b,h).
// XCD swizzle keeps all 128 tiles of a (b,h) on one XCD for K/V L2 locality.
// ---------------------------------------------------------------------------
#define PSTRIDE 264

__global__ __launch_bounds__(256, 2) void attn_kernel(
        const ushort_t* __restrict__ Qh, const ushort_t* __restrict__ Ql,
        const ushort_t* __restrict__ Khi, const ushort_t* __restrict__ Klo,
        const ushort_t* __restrict__ Vth,
        ushort_t* __restrict__ AOh, ushort_t* __restrict__ AOl)
{
    __shared__ __align__(16) ushort_t probs[4 * QT * PSTRIDE];  // 33792 B
    __shared__ __align__(16) unsigned histred[4160];  // hist 16x256 | red 4x16x65
    __shared__ float wsums[4][16];
    __shared__ unsigned prefcur[16];
    __shared__ int kkcur[16];

    const int tid  = threadIdx.x;
    const int lane = tid & 63;
    const int wave = tid >> 6;
    const int qd   = lane >> 4;
    const int c16  = lane & 15;
    // XCD-aware swizzle: tiles of one (b,h) stay on one XCD (blockIdx%8 heuristic)
    const unsigned Bx = blockIdx.x;
    const int xcd  = Bx & 7;
    const int qq   = Bx >> 3;
    const int tile = qq & 127;
    const int bh   = (qq >> 7) * 8 + xcd;
    const int t0   = tile * QT;
    const int wbase = wave * 512;

    if (tid < 16){ prefcur[tid] = 0u; kkcur[tid] = KKSEL; }

    // ---- Q fragments (pre-split by projection) ----
    bf16x8 qh[2], ql[2];
    {
        const size_t qbase = ((size_t)bh * SS + t0 + c16) * DH;
        #pragma unroll
        for (int kc = 0; kc < 2; ++kc){
            qh[kc] = *(const bf16x8*)&Qh[qbase + kc*32 + qd*8];
            ql[kc] = *(const bf16x8*)&Ql[qbase + kc*32 + qd*8];
        }
    }

    // ---- phase 1: scores via split-bf16 MFMA ----
    f32x4 acc[32];
    const ushort_t* Kh = Khi + (size_t)bh * SS * DH;
    const ushort_t* Kl = Klo + (size_t)bh * SS * DH;
    #pragma unroll
    for (int t = 0; t < 32; ++t){
        f32x4 a = {0.f, 0.f, 0.f, 0.f};
        const int srow = wbase + t*16 + c16;
        const ushort_t* kp = Kh + (size_t)srow * DH + qd*8;
        const ushort_t* lp = Kl + (size_t)srow * DH + qd*8;
        #pragma unroll
        for (int kc = 0; kc < 2; ++kc){
            bf16x8 kh = *(const bf16x8*)(kp + kc*32);
            bf16x8 kl = *(const bf16x8*)(lp + kc*32);
            a = __builtin_amdgcn_mfma_f32_16x16x32_bf16(qh[kc], kh, a, 0, 0, 0);
            a = __builtin_amdgcn_mfma_f32_16x16x32_bf16(ql[kc], kh, a, 0, 0, 0);
            a = __builtin_amdgcn_mfma_f32_16x16x32_bf16(qh[kc], kl, a, 0, 0, 0);
        }
        acc[t] = a;
    }

    // ---- scale + diag boost, to sortkeys in place ----
    #pragma unroll
    for (int t = 0; t < 32; ++t){
        const int colg = wbase + t*16 + c16;
        #pragma unroll
        for (int r = 0; r < 4; ++r){
            float v = acc[t][r] * 0.15625f;        // 1/8 * 1.25
            if (colg == t0 + qd*4 + r) v *= 1.15f;
            acc[t][r] = __uint_as_float(sortkey(v));
        }
    }
    __syncthreads();

    // ---- phase 2: exact top-k threshold (radix select) ----
    unsigned* hist = histred;
    #pragma unroll
    for (int pass = 3; pass >= 0; --pass){
        const int sh = pass * 8;
        #pragma unroll
        for (int i = 0; i < 16; ++i) hist[tid + i*256] = 0u;
        unsigned pref[4];
        #pragma unroll
        for (int r = 0; r < 4; ++r) pref[r] = prefcur[qd*4 + r];
        __syncthreads();
        #pragma unroll
        for (int t = 0; t < 32; ++t){
            #pragma unroll
            for (int r = 0; r < 4; ++r){
                const unsigned key = __float_as_uint(acc[t][r]);
                if ((((key ^ pref[r]) >> sh) >> 8) == 0u)   // pass 3: always true
                    atomicAdd(&hist[(qd*4 + r)*256 + ((key >> sh) & 255u)], 1u);
            }
        }
        __syncthreads();
        #pragma unroll
        for (int rr = 0; rr < 4; ++rr){
            const int r = wave*4 + rr;
            uint4 b = *(const uint4*)&hist[r*256 + lane*4];
            unsigned S = b.x + b.y + b.z + b.w;
            #pragma unroll
            for (int off = 1; off < 64; off <<= 1){
                unsigned tmp = __shfl(S, lane + off, 64);
                if (lane + off > 63) tmp = 0u;
                S += tmp;
            }
            const unsigned ku = (unsigned)kkcur[r];
            const unsigned cum0 = S;
            const unsigned cum1 = cum0 - b.x;
            const unsigned cum2 = cum1 - b.y;
            const unsigned cum3 = cum2 - b.z;
            const unsigned cum4 = cum3 - b.w;
            int j = -1; unsigned cn = 0;
            if      (cum0 >= ku && cum1 < ku){ j = 0; cn = cum1; }
            else if (cum1 >= ku && cum2 < ku){ j = 1; cn = cum2; }
            else if (cum2 >= ku && cum3 < ku){ j = 2; cn = cum3; }
            else if (cum3 >= ku && cum4 < ku){ j = 3; cn = cum4; }
            if (j >= 0){
                prefcur[r] |= (unsigned)(lane*4 + j) << sh;
                kkcur[r] = (int)(ku - cn);
            }
        }
        __syncthreads();
    }

    // ---- phase 3: boost + exp + row sums ----
    unsigned thr[4];
    #pragma unroll
    for (int r = 0; r < 4; ++r) thr[r] = prefcur[qd*4 + r];
    float psum[4] = {0.f, 0.f, 0.f, 0.f};
    #pragma unroll
    for (int t = 0; t < 32; ++t){
        #pragma unroll
        for (int r = 0; r < 4; ++r){
            const unsigned key = __float_as_uint(acc[t][r]);
            float s = inv_sortkey(key);
            s *= (key >= thr[r]) ? 1.15f : 1.0f;
            const float e = __expf(s);
            acc[t][r] = e;
            psum[r] += e;
        }
    }
    #pragma unroll
    for (int off = 1; off <= 8; off <<= 1){
        #pragma unroll
        for (int r = 0; r < 4; ++r) psum[r] += __shfl_xor(psum[r], off, 64);
    }
    if (c16 == 0){
        #pragma unroll
        for (int r = 0; r < 4; ++r) wsums[wave][qd*4 + r] = psum[r];
    }
    __syncthreads();
    float pinv[4];
    #pragma unroll
    for (int r = 0; r < 4; ++r){
        const int row = qd*4 + r;
        pinv[r] = 1.f / (wsums[0][row] + wsums[1][row] + wsums[2][row] + wsums[3][row]);
    }

    // ---- phase 4: O = P @ V (bf16 V, hi only) ----
    const ushort_t* Vh = Vth + (size_t)bh * DH * SS;
    ushort_t* pw = probs + wave * (QT * PSTRIDE);
    f32x4 oacc[4];
    #pragma unroll
    for (int dt = 0; dt < 4; ++dt) oacc[dt] = (f32x4){0.f, 0.f, 0.f, 0.f};

    #pragma unroll
    for (int half = 0; half < 2; ++half){
        #pragma unroll
        for (int tt = 0; tt < 16; ++tt){
            const int t = half*16 + tt;
            #pragma unroll
            for (int r = 0; r < 4; ++r)
                pw[(qd*4 + r) * PSTRIDE + tt*16 + c16] = f2bf(acc[t][r] * pinv[r]);
        }
        #pragma unroll
        for (int kc = 0; kc < 8; ++kc){
            bf16x8 pf = *(const bf16x8*)&pw[c16 * PSTRIDE + kc*32 + qd*8];
            const int sbase = wbase + half*256 + kc*32 + qd*8;
            #pragma unroll
            for (int dt = 0; dt < 4; ++dt){
                const int d = dt*16 + c16;
                bf16x8 vh = *(const bf16x8*)(Vh + (size_t)d * SS + sbase);
                oacc[dt] = __builtin_amdgcn_mfma_f32_16x16x32_bf16(pf, vh, oacc[dt], 0, 0, 0);
            }
        }
    }

    // ---- cross-wave O reduction + split-bf16 store ----
    __syncthreads();   // probs reads done before red overwrites the union
    float* red = (float*)histred;   // 4 x 16 x 65
    #pragma unroll
    for (int dt = 0; dt < 4; ++dt)
        #pragma unroll
        for (int r = 0; r < 4; ++r)
            red[(wave*16 + qd*4 + r) * 65 + dt*16 + c16] = oacc[dt][r];
    __syncthreads();

    const int b = bh >> 4, h = bh & 15;
    {
        const int r  = tid >> 4;
        const int c4 = (tid & 15) * 4;
        ushort4 oh, ol;
        ushort_t* ohp = &oh.x; ushort_t* olp = &ol.x;
        #pragma unroll
        for (int j = 0; j < 4; ++j){
            float s = 0.f;
            #pragma unroll
            for (int w = 0; w < 4; ++w) s += red[(w*16 + r) * 65 + c4 + j];
            ushort_t hh = f2bf(s);
            ohp[j] = hh;
            olp[j] = f2bf(s - bf2f(hh));
        }
        const size_t o = ((size_t)b * SS + t0 + r) * EE + h*DH + c4;
        *(ushort4*)&AOh[o] = oh;
        *(ushort4*)&AOl[o] = ol;
    }
}

// ---------------------------------------------------------------------------
extern "C" void kernel_launch(void* const* d_in, const int* in_sizes, int n_in,
                              void* d_out, int out_size, void* d_ws, size_t ws_size,
                              hipStream_t stream)
{
    const float* query = (const float*)d_in[0];
    const float* key   = (const float*)d_in[1];
    const float* value = (const float*)d_in[2];
    const float* Wq    = (const float*)d_in[3];
    const float* bq    = (const float*)d_in[4];
    const float* Wk    = (const float*)d_in[5];
    const float* bk    = (const float*)d_in[6];
    const float* Wv    = (const float*)d_in[7];
    const float* bv    = (const float*)d_in[8];
    const float* Wo    = (const float*)d_in[9];
    const float* bo    = (const float*)d_in[10];
    const float* ts    = (const float*)d_in[11];
    float* out = (float*)d_out;
    char* w = (char*)d_ws;

    const size_t MB = 1u << 20;
    ushort_t* Qh  = (ushort_t*)(w + 0 * MB);
    ushort_t* Ql  = (ushort_t*)(w + 8 * MB);
    ushort_t* Kh  = (ushort_t*)(w + 16 * MB);
    ushort_t* Kl  = (ushort_t*)(w + 24 * MB);
    ushort_t* Vth = (ushort_t*)(w + 32 * MB);
    ushort_t* Xh  = (ushort_t*)(w + 40 * MB);  // aliased: X-split scratch, then AOh
    ushort_t* Xl  = (ushort_t*)(w + 48 * MB);  // aliased: X-split scratch, then AOl
    ushort_t* Wth = (ushort_t*)(w + 56 * MB);
    ushort_t* Wtl = (ushort_t*)(w + 58 * MB);

    dim3 cb(256);
    dim3 cxg(4096);            // convert_x: 4M elems / (256*4)
    dim3 wtg(16, 16);          // convert_wt: 64x64 tiles
    dim3 gg(8, 32), gb(256);   // gemm: N/128 x M/128

    // Q projection
    hipLaunchKernelGGL(convert_x, cxg, cb, 0, stream, query, Xh, Xl);
    hipLaunchKernelGGL(convert_wt, wtg, cb, 0, stream, Wq, Wth, Wtl);
    hipLaunchKernelGGL((gemm_mfma<0>), gg, gb, 0, stream, Xh, Xl, Wth, Wtl, bq, nullptr,
                       nullptr, Qh, Ql);
    // K projection (scaled by time_scales)
    hipLaunchKernelGGL(convert_x, cxg, cb, 0, stream, key, Xh, Xl);
    hipLaunchKernelGGL(convert_wt, wtg, cb, 0, stream, Wk, Wth, Wtl);
    hipLaunchKernelGGL((gemm_mfma<1>), gg, gb, 0, stream, Xh, Xl, Wth, Wtl, bk, ts,
                       nullptr, Kh, Kl);
    // V projection (transposed, hi only)
    hipLaunchKernelGGL(convert_x, cxg, cb, 0, stream, value, Xh, Xl);
    hipLaunchKernelGGL(convert_wt, wtg, cb, 0, stream, Wv, Wth, Wtl);
    hipLaunchKernelGGL((gemm_mfma<2>), gg, gb, 0, stream, Xh, Xl, Wth, Wtl, bv, nullptr,
                       nullptr, Vth, nullptr);
    // attention (writes AO split into Xh/Xl region)
    hipLaunchKernelGGL(attn_kernel, dim3(BB * HH * (SS / QT)), dim3(256), 0, stream,
                       Qh, Ql, Kh, Kl, Vth, Xh, Xl);
    // output projection
    hipLaunchKernelGGL(convert_wt, wtg, cb, 0, stream, Wo, Wth, Wtl);
    hipLaunchKernelGGL((gemm_mfma<3>), gg, gb, 0, stream, Xh, Xl, Wth, Wtl, bo, nullptr,
                       out, nullptr, nullptr);
}

// Round 4
// 807.216 us; speedup vs baseline: 2.1874x; 1.1860x over previous
//
#include <hip/hip_runtime.h>
#include <cstdint>
#include <cstddef>

#define BB 2
#define SS 2048
#define EE 1024
#define HH 16
#define DH 64
#define KKSEL 409   // kk = int(2048*0.2)
#define QT 16       // query rows per attention block
#define PST 136     // probs LDS row stride (bf16 elems) per half (128 cols + pad)

typedef __attribute__((ext_vector_type(8))) short bf16x8;
typedef __attribute__((ext_vector_type(4))) float f32x4;
typedef unsigned short ushort_t;

__device__ __forceinline__ unsigned short f2bf(float f){
    unsigned u = __float_as_uint(f);
    u += 0x7fffu + ((u >> 16) & 1u);          // RNE
    return (unsigned short)(u >> 16);
}
__device__ __forceinline__ float bf2f(unsigned short h){
    return __uint_as_float(((unsigned)h) << 16);
}
__device__ __forceinline__ unsigned sortkey(float f){
    unsigned u = __float_as_uint(f);
    return (u & 0x80000000u) ? ~u : (u | 0x80000000u);
}
__device__ __forceinline__ float inv_sortkey(unsigned k){
    unsigned u = (k & 0x80000000u) ? (k & 0x7fffffffu) : ~k;
    return __uint_as_float(u);
}

// ---------------------------------------------------------------------------
// convert_x: fp32 (4096x1024 flat) -> bf16 hi + lo, same layout
// ---------------------------------------------------------------------------
__global__ __launch_bounds__(256) void convert_x(const float* __restrict__ X,
                                                 ushort_t* __restrict__ H,
                                                 ushort_t* __restrict__ L)
{
    const int i = (blockIdx.x * 256 + threadIdx.x) * 4;
    float4 v = *(const float4*)&X[i];
    const float f[4] = {v.x, v.y, v.z, v.w};
    ushort4 h, l;
    ushort_t* hp = &h.x; ushort_t* lp = &l.x;
    #pragma unroll
    for (int j = 0; j < 4; ++j){
        ushort_t hh = f2bf(f[j]);
        hp[j] = hh;
        lp[j] = f2bf(f[j] - bf2f(hh));
    }
    *(ushort4*)&H[i] = h;
    *(ushort4*)&L[i] = l;
}

// ---------------------------------------------------------------------------
// convert_wt: W (1024x1024 [k][n]) -> W^T bf16 hi/lo ([n][k])
// ---------------------------------------------------------------------------
__global__ __launch_bounds__(256) void convert_wt(const float* __restrict__ W,
                                                  ushort_t* __restrict__ Ht,
                                                  ushort_t* __restrict__ Lt)
{
    __shared__ float T[64][65];
    const int tid = threadIdx.x;
    const int ty = tid >> 4, tx = tid & 15;
    const int n0 = blockIdx.x * 64, k0 = blockIdx.y * 64;
    #pragma unroll
    for (int i = 0; i < 4; ++i){
        const int kl = ty + i * 16;
        float4 w = *(const float4*)&W[(size_t)(k0 + kl) * EE + n0 + tx * 4];
        T[kl][tx*4 + 0] = w.x; T[kl][tx*4 + 1] = w.y;
        T[kl][tx*4 + 2] = w.z; T[kl][tx*4 + 3] = w.w;
    }
    __syncthreads();
    #pragma unroll
    for (int i = 0; i < 4; ++i){
        const int nl = ty + i * 16;
        ushort4 h, l;
        ushort_t* hp = &h.x; ushort_t* lp = &l.x;
        #pragma unroll
        for (int j = 0; j < 4; ++j){
            const float v = T[tx*4 + j][nl];
            ushort_t hh = f2bf(v);
            hp[j] = hh;
            lp[j] = f2bf(v - bf2f(hh));
        }
        const size_t o = (size_t)(n0 + nl) * EE + k0 + tx * 4;
        *(ushort4*)&Ht[o] = h;
        *(ushort4*)&Lt[o] = l;
    }
}

// ---------------------------------------------------------------------------
// Split-bf16 MFMA GEMM: C = X(4096x1024) @ W(1024x1024) + bias
// MODE 0: Q  -> bf16 hi/lo [bh][s][d]
// MODE 1: K  -> bf16 hi ONLY [bh][s][d], scaled by ts[h]
// MODE 2: V  -> bf16 hi only, transposed [bh][d][s]
// MODE 3: fp32 row-major (final projection -> d_out)
// ---------------------------------------------------------------------------
template<int MODE>
__global__ __launch_bounds__(256) void gemm_mfma(
        const ushort_t* __restrict__ Xh, const ushort_t* __restrict__ Xl,
        const ushort_t* __restrict__ Wth, const ushort_t* __restrict__ Wtl,
        const float* __restrict__ bias, const float* __restrict__ ts,
        float* __restrict__ OutF, ushort_t* __restrict__ OutH,
        ushort_t* __restrict__ OutL)
{
    __shared__ ushort_t buf[2][16384];   // [stage][Ah|Al|Bh|Bl], 32 KB each
    const int tid  = threadIdx.x;
    const int lane = tid & 63, wave = tid >> 6;
    const int c16  = lane & 15, qd = lane >> 4;
    const int m0 = blockIdx.y * 128, n0 = blockIdx.x * 128;
    const int wm = (wave >> 1) * 64, wn = (wave & 1) * 64;
    const int lrow = tid >> 1, lkg = (tid & 1) * 16;

    f32x4 acc[4][4];
    #pragma unroll
    for (int a = 0; a < 4; ++a)
        #pragma unroll
        for (int b = 0; b < 4; ++b) acc[a][b] = (f32x4){0.f,0.f,0.f,0.f};

    {
        const size_t xo = (size_t)(m0 + lrow) * EE + lkg;
        const size_t wo = (size_t)(n0 + lrow) * EE + lkg;
        bf16x8 x0 = *(const bf16x8*)&Xh[xo];
        bf16x8 x1 = *(const bf16x8*)&Xh[xo + 8];
        bf16x8 x2 = *(const bf16x8*)&Xl[xo];
        bf16x8 x3 = *(const bf16x8*)&Xl[xo + 8];
        bf16x8 w0 = *(const bf16x8*)&Wth[wo];
        bf16x8 w1 = *(const bf16x8*)&Wth[wo + 8];
        bf16x8 w2 = *(const bf16x8*)&Wtl[wo];
        bf16x8 w3 = *(const bf16x8*)&Wtl[wo + 8];
        *(bf16x8*)&buf[0][lrow*32 + lkg]          = x0;
        *(bf16x8*)&buf[0][lrow*32 + lkg + 8]      = x1;
        *(bf16x8*)&buf[0][4096 + lrow*32 + lkg]   = x2;
        *(bf16x8*)&buf[0][4096 + lrow*32 + lkg+8] = x3;
        *(bf16x8*)&buf[0][8192 + lrow*32 + lkg]   = w0;
        *(bf16x8*)&buf[0][8192 + lrow*32 + lkg+8] = w1;
        *(bf16x8*)&buf[0][12288 + lrow*32 + lkg]  = w2;
        *(bf16x8*)&buf[0][12288 + lrow*32 + lkg+8]= w3;
    }
    __syncthreads();

    int cur = 0;
    for (int k0 = 0; k0 < EE; k0 += 32){
        const bool more = (k0 + 32) < EE;
        bf16x8 g[8];
        if (more){
            const size_t xo = (size_t)(m0 + lrow) * EE + k0 + 32 + lkg;
            const size_t wo = (size_t)(n0 + lrow) * EE + k0 + 32 + lkg;
            g[0] = *(const bf16x8*)&Xh[xo];  g[1] = *(const bf16x8*)&Xh[xo + 8];
            g[2] = *(const bf16x8*)&Xl[xo];  g[3] = *(const bf16x8*)&Xl[xo + 8];
            g[4] = *(const bf16x8*)&Wth[wo]; g[5] = *(const bf16x8*)&Wth[wo + 8];
            g[6] = *(const bf16x8*)&Wtl[wo]; g[7] = *(const bf16x8*)&Wtl[wo + 8];
        }
        const ushort_t* A0 = &buf[cur][0];
        const ushort_t* A1 = &buf[cur][4096];
        const ushort_t* B0 = &buf[cur][8192];
        const ushort_t* B1 = &buf[cur][12288];
        bf16x8 afh[4], afl[4], bfh[4], bfl[4];
        #pragma unroll
        for (int i = 0; i < 4; ++i){
            afh[i] = *(const bf16x8*)&A0[(wm + i*16 + c16)*32 + qd*8];
            afl[i] = *(const bf16x8*)&A1[(wm + i*16 + c16)*32 + qd*8];
            bfh[i] = *(const bf16x8*)&B0[(wn + i*16 + c16)*32 + qd*8];
            bfl[i] = *(const bf16x8*)&B1[(wn + i*16 + c16)*32 + qd*8];
        }
        #pragma unroll
        for (int a = 0; a < 4; ++a){
            #pragma unroll
            for (int b = 0; b < 4; ++b){
                if (MODE == 2){
                    acc[a][b] = __builtin_amdgcn_mfma_f32_16x16x32_bf16(afh[a], bfh[b], acc[a][b], 0,0,0);
                    acc[a][b] = __builtin_amdgcn_mfma_f32_16x16x32_bf16(afh[a], bfl[b], acc[a][b], 0,0,0);
                    acc[a][b] = __builtin_amdgcn_mfma_f32_16x16x32_bf16(afl[a], bfh[b], acc[a][b], 0,0,0);
                } else {
                    acc[a][b] = __builtin_amdgcn_mfma_f32_16x16x32_bf16(bfh[a], afh[b], acc[a][b], 0,0,0);
                    acc[a][b] = __builtin_amdgcn_mfma_f32_16x16x32_bf16(bfh[a], afl[b], acc[a][b], 0,0,0);
                    acc[a][b] = __builtin_amdgcn_mfma_f32_16x16x32_bf16(bfl[a], afh[b], acc[a][b], 0,0,0);
                }
            }
        }
        if (more){
            ushort_t* N = &buf[cur ^ 1][0];
            *(bf16x8*)&N[lrow*32 + lkg]           = g[0];
            *(bf16x8*)&N[lrow*32 + lkg + 8]       = g[1];
            *(bf16x8*)&N[4096 + lrow*32 + lkg]    = g[2];
            *(bf16x8*)&N[4096 + lrow*32 + lkg+8]  = g[3];
            *(bf16x8*)&N[8192 + lrow*32 + lkg]    = g[4];
            *(bf16x8*)&N[8192 + lrow*32 + lkg+8]  = g[5];
            *(bf16x8*)&N[12288 + lrow*32 + lkg]   = g[6];
            *(bf16x8*)&N[12288 + lrow*32 + lkg+8] = g[7];
            __syncthreads();
            cur ^= 1;
        }
    }

    if (MODE == 3){
        #pragma unroll
        for (int a = 0; a < 4; ++a){
            const int ng = n0 + wn + a*16 + qd*4;
            float4 b4 = *(const float4*)&bias[ng];
            const float bb[4] = {b4.x, b4.y, b4.z, b4.w};
            #pragma unroll
            for (int b = 0; b < 4; ++b){
                const int mg = m0 + wm + b*16 + c16;
                float4 o;
                o.x = acc[a][b][0] + bb[0]; o.y = acc[a][b][1] + bb[1];
                o.z = acc[a][b][2] + bb[2]; o.w = acc[a][b][3] + bb[3];
                *(float4*)&OutF[(size_t)mg * EE + ng] = o;
            }
        }
    } else if (MODE == 0){
        #pragma unroll
        for (int a = 0; a < 4; ++a){
            const int ng = n0 + wn + a*16 + qd*4;
            const int h = ng >> 6, d0 = ng & 63;
            float4 b4 = *(const float4*)&bias[ng];
            const float bb[4] = {b4.x, b4.y, b4.z, b4.w};
            #pragma unroll
            for (int b = 0; b < 4; ++b){
                const int mg = m0 + wm + b*16 + c16;
                const int bi = mg >> 11, s = mg & (SS - 1);
                ushort4 hv, lv;
                ushort_t* hp = &hv.x; ushort_t* lp = &lv.x;
                #pragma unroll
                for (int r = 0; r < 4; ++r){
                    const float v = acc[a][b][r] + bb[r];
                    ushort_t hh = f2bf(v);
                    hp[r] = hh;
                    lp[r] = f2bf(v - bf2f(hh));
                }
                const size_t o = (((size_t)(bi * HH + h)) * SS + s) * DH + d0;
                *(ushort4*)&OutH[o] = hv;
                *(ushort4*)&OutL[o] = lv;
            }
        }
    } else if (MODE == 1){
        #pragma unroll
        for (int a = 0; a < 4; ++a){
            const int ng = n0 + wn + a*16 + qd*4;
            const int h = ng >> 6, d0 = ng & 63;
            const float tsc = ts[h];
            float4 b4 = *(const float4*)&bias[ng];
            const float bb[4] = {b4.x, b4.y, b4.z, b4.w};
            #pragma unroll
            for (int b = 0; b < 4; ++b){
                const int mg = m0 + wm + b*16 + c16;
                const int bi = mg >> 11, s = mg & (SS - 1);
                ushort4 hv;
                ushort_t* hp = &hv.x;
                #pragma unroll
                for (int r = 0; r < 4; ++r)
                    hp[r] = f2bf((acc[a][b][r] + bb[r]) * tsc);
                *(ushort4*)&OutH[(((size_t)(bi * HH + h)) * SS + s) * DH + d0] = hv;
            }
        }
    } else { // MODE 2: V^T hi only
        #pragma unroll
        for (int a = 0; a < 4; ++a){
            const int mg = m0 + wm + a*16 + qd*4;
            const int bi = mg >> 11, s0 = mg & (SS - 1);
            #pragma unroll
            for (int b = 0; b < 4; ++b){
                const int ng = n0 + wn + b*16 + c16;
                const int h = ng >> 6, d = ng & 63;
                const float bv = bias[ng];
                ushort4 hv;
                ushort_t* hp = &hv.x;
                #pragma unroll
                for (int r = 0; r < 4; ++r) hp[r] = f2bf(acc[a][b][r] + bv);
                *(ushort4*)&OutH[(((size_t)(bi * HH + h)) * DH + d) * SS + s0] = hv;
            }
        }
    }
}

// ---------------------------------------------------------------------------
// Fused attention, 512 threads / 8 waves; wave owns 256 score columns.
// acc[16] (64 AGPR/lane) -> combined regs ~110 -> 4 waves/SIMD (16 waves/CU).
// LDS: probs / hist / red share one union (phases strictly ordered).
// ---------------------------------------------------------------------------
__global__ __launch_bounds__(512, 4) void attn_kernel(
        const ushort_t* __restrict__ Qh, const ushort_t* __restrict__ Ql,
        const ushort_t* __restrict__ Khi, const ushort_t* __restrict__ Vth,
        ushort_t* __restrict__ AOh, ushort_t* __restrict__ AOl)
{
    // union: hist 16x256 u32 (16384) | probs 8 waves x 16 x PST bf16 (34816)
    //        | red 8 x 16 x 65 f32 (33280)
    __shared__ __align__(16) char uni[34816];
    __shared__ float wsums[8][16];
    __shared__ unsigned prefcur[16];
    __shared__ int kkcur[16];

    const int tid  = threadIdx.x;
    const int lane = tid & 63;
    const int wave = tid >> 6;
    const int qd   = lane >> 4;
    const int c16  = lane & 15;
    const unsigned Bx = blockIdx.x;
    const int xcd  = Bx & 7;
    const int qq   = Bx >> 3;
    const int tile = qq & 127;
    const int bh   = (qq >> 7) * 8 + xcd;
    const int t0   = tile * QT;
    const int wbase = wave * 256;

    if (tid < 16){ prefcur[tid] = 0u; kkcur[tid] = KKSEL; }

    // ---- Q fragments (pre-split hi/lo) ----
    bf16x8 qh[2], ql[2];
    {
        const size_t qbase = ((size_t)bh * SS + t0 + c16) * DH;
        #pragma unroll
        for (int kc = 0; kc < 2; ++kc){
            qh[kc] = *(const bf16x8*)&Qh[qbase + kc*32 + qd*8];
            ql[kc] = *(const bf16x8*)&Ql[qbase + kc*32 + qd*8];
        }
    }

    // ---- phase 1: scores (K hi-only, Q split) ----
    f32x4 acc[16];
    const ushort_t* Kh = Khi + (size_t)bh * SS * DH;
    #pragma unroll
    for (int t = 0; t < 16; ++t){
        f32x4 a = {0.f, 0.f, 0.f, 0.f};
        const int srow = wbase + t*16 + c16;
        const ushort_t* kp = Kh + (size_t)srow * DH + qd*8;
        #pragma unroll
        for (int kc = 0; kc < 2; ++kc){
            bf16x8 kh = *(const bf16x8*)(kp + kc*32);
            a = __builtin_amdgcn_mfma_f32_16x16x32_bf16(qh[kc], kh, a, 0, 0, 0);
            a = __builtin_amdgcn_mfma_f32_16x16x32_bf16(ql[kc], kh, a, 0, 0, 0);
        }
        acc[t] = a;
    }

    // ---- scale + diag boost, to sortkeys in place ----
    #pragma unroll
    for (int t = 0; t < 16; ++t){
        const int colg = wbase + t*16 + c16;
        #pragma unroll
        for (int r = 0; r < 4; ++r){
            float v = acc[t][r] * 0.15625f;        // 1/8 * 1.25
            if (colg == t0 + qd*4 + r) v *= 1.15f;
            acc[t][r] = __uint_as_float(sortkey(v));
        }
    }
    __syncthreads();

    // ---- phase 2: exact top-k threshold (radix select) ----
    unsigned* hist = (unsigned*)uni;   // 16 rows x 256 bins
    #pragma unroll
    for (int pass = 3; pass >= 0; --pass){
        const int sh = pass * 8;
        #pragma unroll
        for (int i = 0; i < 8; ++i) hist[tid + i*512] = 0u;
        unsigned pref[4];
        #pragma unroll
        for (int r = 0; r < 4; ++r) pref[r] = prefcur[qd*4 + r];
        __syncthreads();
        #pragma unroll
        for (int t = 0; t < 16; ++t){
            #pragma unroll
            for (int r = 0; r < 4; ++r){
                const unsigned key = __float_as_uint(acc[t][r]);
                if ((((key ^ pref[r]) >> sh) >> 8) == 0u)   // pass 3: always true
                    atomicAdd(&hist[(qd*4 + r)*256 + ((key >> sh) & 255u)], 1u);
            }
        }
        __syncthreads();
        #pragma unroll
        for (int rr = 0; rr < 2; ++rr){
            const int r = wave*2 + rr;
            uint4 b = *(const uint4*)&hist[r*256 + lane*4];
            unsigned S = b.x + b.y + b.z + b.w;
            #pragma unroll
            for (int off = 1; off < 64; off <<= 1){
                unsigned tmp = __shfl(S, lane + off, 64);
                if (lane + off > 63) tmp = 0u;
                S += tmp;
            }
            const unsigned ku = (unsigned)kkcur[r];
            const unsigned cum0 = S;
            const unsigned cum1 = cum0 - b.x;
            const unsigned cum2 = cum1 - b.y;
            const unsigned cum3 = cum2 - b.z;
            const unsigned cum4 = cum3 - b.w;
            int j = -1; unsigned cn = 0;
            if      (cum0 >= ku && cum1 < ku){ j = 0; cn = cum1; }
            else if (cum1 >= ku && cum2 < ku){ j = 1; cn = cum2; }
            else if (cum2 >= ku && cum3 < ku){ j = 2; cn = cum3; }
            else if (cum3 >= ku && cum4 < ku){ j = 3; cn = cum4; }
            if (j >= 0){
                prefcur[r] |= (unsigned)(lane*4 + j) << sh;
                kkcur[r] = (int)(ku - cn);
            }
        }
        __syncthreads();
    }

    // ---- phase 3: boost + exp + row sums ----
    unsigned thr[4];
    #pragma unroll
    for (int r = 0; r < 4; ++r) thr[r] = prefcur[qd*4 + r];
    float psum[4] = {0.f, 0.f, 0.f, 0.f};
    #pragma unroll
    for (int t = 0; t < 16; ++t){
        #pragma unroll
        for (int r = 0; r < 4; ++r){
            const unsigned key = __float_as_uint(acc[t][r]);
            float s = inv_sortkey(key);
            s *= (key >= thr[r]) ? 1.15f : 1.0f;
            const float e = __expf(s);
            acc[t][r] = e;
            psum[r] += e;
        }
    }
    #pragma unroll
    for (int off = 1; off <= 8; off <<= 1){
        #pragma unroll
        for (int r = 0; r < 4; ++r) psum[r] += __shfl_xor(psum[r], off, 64);
    }
    if (c16 == 0){
        #pragma unroll
        for (int r = 0; r < 4; ++r) wsums[wave][qd*4 + r] = psum[r];
    }
    __syncthreads();
    float pinv[4];
    #pragma unroll
    for (int r = 0; r < 4; ++r){
        const int row = qd*4 + r;
        float s = 0.f;
        #pragma unroll
        for (int w = 0; w < 8; ++w) s += wsums[w][row];
        pinv[r] = 1.f / s;
    }
    __syncthreads();   // hist reads fully done before probs overwrite the union

    // ---- phase 4: O = P @ V (two 128-col halves per wave) ----
    const ushort_t* Vh = Vth + (size_t)bh * DH * SS;
    ushort_t* pw = (ushort_t*)uni + wave * (QT * PST);
    f32x4 oacc[4];
    #pragma unroll
    for (int dt = 0; dt < 4; ++dt) oacc[dt] = (f32x4){0.f, 0.f, 0.f, 0.f};

    #pragma unroll
    for (int half = 0; half < 2; ++half){
        #pragma unroll
        for (int tt = 0; tt < 8; ++tt){
            const int t = half*8 + tt;
            #pragma unroll
            for (int r = 0; r < 4; ++r)
                pw[(qd*4 + r) * PST + tt*16 + c16] = f2bf(acc[t][r] * pinv[r]);
        }
        // per-wave region: same-wave ds_write -> ds_read, no barrier needed
        #pragma unroll
        for (int kc = 0; kc < 4; ++kc){
            bf16x8 pf = *(const bf16x8*)&pw[c16 * PST + kc*32 + qd*8];
            const int sbase = wbase + half*128 + kc*32 + qd*8;
            #pragma unroll
            for (int dt = 0; dt < 4; ++dt){
                const int d = dt*16 + c16;
                bf16x8 vh = *(const bf16x8*)(Vh + (size_t)d * SS + sbase);
                oacc[dt] = __builtin_amdgcn_mfma_f32_16x16x32_bf16(pf, vh, oacc[dt], 0, 0, 0);
            }
        }
    }

    // ---- cross-wave O reduction + split-bf16 store ----
    __syncthreads();   // all probs reads done before red overwrites the union
    float* red = (float*)uni;   // 8 x 16 x 65
    #pragma unroll
    for (int dt = 0; dt < 4; ++dt)
        #pragma unroll
        for (int r = 0; r < 4; ++r)
            red[(wave*16 + qd*4 + r) * 65 + dt*16 + c16] = oacc[dt][r];
    __syncthreads();

    const int b = bh >> 4, h = bh & 15;
    if (tid < 256){
        const int r  = tid >> 4;
        const int c4 = (tid & 15) * 4;
        ushort4 oh, ol;
        ushort_t* ohp = &oh.x; ushort_t* olp = &ol.x;
        #pragma unroll
        for (int j = 0; j < 4; ++j){
            float s = 0.f;
            #pragma unroll
            for (int w = 0; w < 8; ++w) s += red[(w*16 + r) * 65 + c4 + j];
            ushort_t hh = f2bf(s);
            ohp[j] = hh;
            olp[j] = f2bf(s - bf2f(hh));
        }
        const size_t o = ((size_t)b * SS + t0 + r) * EE + h*DH + c4;
        *(ushort4*)&AOh[o] = oh;
        *(ushort4*)&AOl[o] = ol;
    }
}

// ---------------------------------------------------------------------------
extern "C" void kernel_launch(void* const* d_in, const int* in_sizes, int n_in,
                              void* d_out, int out_size, void* d_ws, size_t ws_size,
                              hipStream_t stream)
{
    const float* query = (const float*)d_in[0];
    const float* key   = (const float*)d_in[1];
    const float* value = (const float*)d_in[2];
    const float* Wq    = (const float*)d_in[3];
    const float* bq    = (const float*)d_in[4];
    const float* Wk    = (const float*)d_in[5];
    const float* bk    = (const float*)d_in[6];
    const float* Wv    = (const float*)d_in[7];
    const float* bv    = (const float*)d_in[8];
    const float* Wo    = (const float*)d_in[9];
    const float* bo    = (const float*)d_in[10];
    const float* ts    = (const float*)d_in[11];
    float* out = (float*)d_out;
    char* w = (char*)d_ws;

    const size_t MB = 1u << 20;
    ushort_t* Qh  = (ushort_t*)(w + 0 * MB);
    ushort_t* Ql  = (ushort_t*)(w + 8 * MB);
    ushort_t* Kh  = (ushort_t*)(w + 16 * MB);
    ushort_t* Vth = (ushort_t*)(w + 24 * MB);
    ushort_t* Xh  = (ushort_t*)(w + 32 * MB);  // aliased: X-split scratch, then AOh
    ushort_t* Xl  = (ushort_t*)(w + 40 * MB);  // aliased: X-split scratch, then AOl
    ushort_t* Wth = (ushort_t*)(w + 48 * MB);
    ushort_t* Wtl = (ushort_t*)(w + 50 * MB);

    dim3 cb(256);
    dim3 cxg(4096);            // convert_x: 4M elems / (256*4)
    dim3 wtg(16, 16);          // convert_wt: 64x64 tiles
    dim3 gg(8, 32), gb(256);   // gemm: N/128 x M/128

    // Q projection
    hipLaunchKernelGGL(convert_x, cxg, cb, 0, stream, query, Xh, Xl);
    hipLaunchKernelGGL(convert_wt, wtg, cb, 0, stream, Wq, Wth, Wtl);
    hipLaunchKernelGGL((gemm_mfma<0>), gg, gb, 0, stream, Xh, Xl, Wth, Wtl, bq, nullptr,
                       nullptr, Qh, Ql);
    // K projection (scaled, hi only)
    hipLaunchKernelGGL(convert_x, cxg, cb, 0, stream, key, Xh, Xl);
    hipLaunchKernelGGL(convert_wt, wtg, cb, 0, stream, Wk, Wth, Wtl);
    hipLaunchKernelGGL((gemm_mfma<1>), gg, gb, 0, stream, Xh, Xl, Wth, Wtl, bk, ts,
                       nullptr, Kh, nullptr);
    // V projection (transposed, hi only)
    hipLaunchKernelGGL(convert_x, cxg, cb, 0, stream, value, Xh, Xl);
    hipLaunchKernelGGL(convert_wt, wtg, cb, 0, stream, Wv, Wth, Wtl);
    hipLaunchKernelGGL((gemm_mfma<2>), gg, gb, 0, stream, Xh, Xl, Wth, Wtl, bv, nullptr,
                       nullptr, Vth, nullptr);
    // attention (writes AO split into Xh/Xl region)
    hipLaunchKernelGGL(attn_kernel, dim3(BB * HH * (SS / QT)), dim3(512), 0, stream,
                       Qh, Ql, Kh, Vth, Xh, Xl);
    // output projection
    hipLaunchKernelGGL(convert_wt, wtg, cb, 0, stream, Wo, Wth, Wtl);
    hipLaunchKernelGGL((gemm_mfma<3>), gg, gb, 0, stream, Xh, Xl, Wth, Wtl, bo, nullptr,
                       out, nullptr, nullptr);
}

// Round 5
// 779.783 us; speedup vs baseline: 2.2644x; 1.0352x over previous
//
#include <hip/hip_runtime.h>
#include <cstdint>
#include <cstddef>

#define BB 2
#define SS 2048
#define EE 1024
#define HH 16
#define DH 64
#define KKSEL 409   // kk = int(2048*0.2)
#define QT 16       // query rows per attention block
#define PST 136     // probs LDS row stride (bf16 elems) per half (128 cols + pad)

typedef __attribute__((ext_vector_type(8))) short bf16x8;
typedef __attribute__((ext_vector_type(4))) float f32x4;
typedef unsigned short ushort_t;

__device__ __forceinline__ unsigned short f2bf(float f){
    unsigned u = __float_as_uint(f);
    u += 0x7fffu + ((u >> 16) & 1u);          // RNE
    return (unsigned short)(u >> 16);
}
__device__ __forceinline__ float bf2f(unsigned short h){
    return __uint_as_float(((unsigned)h) << 16);
}
__device__ __forceinline__ unsigned sortkey(float f){
    unsigned u = __float_as_uint(f);
    return (u & 0x80000000u) ? ~u : (u | 0x80000000u);
}
__device__ __forceinline__ float inv_sortkey(unsigned k){
    unsigned u = (k & 0x80000000u) ? (k & 0x7fffffffu) : ~k;
    return __uint_as_float(u);
}

// ---------------------------------------------------------------------------
// convert_x: fp32 (4096x1024 flat) -> bf16 hi + lo, same layout
// ---------------------------------------------------------------------------
__global__ __launch_bounds__(256) void convert_x(const float* __restrict__ X,
                                                 ushort_t* __restrict__ H,
                                                 ushort_t* __restrict__ L)
{
    const int i = (blockIdx.x * 256 + threadIdx.x) * 4;
    float4 v = *(const float4*)&X[i];
    const float f[4] = {v.x, v.y, v.z, v.w};
    ushort4 h, l;
    ushort_t* hp = &h.x; ushort_t* lp = &l.x;
    #pragma unroll
    for (int j = 0; j < 4; ++j){
        ushort_t hh = f2bf(f[j]);
        hp[j] = hh;
        lp[j] = f2bf(f[j] - bf2f(hh));
    }
    *(ushort4*)&H[i] = h;
    *(ushort4*)&L[i] = l;
}

// ---------------------------------------------------------------------------
// convert_wt: W (1024x1024 [k][n]) -> W^T bf16 hi/lo ([n][k])
// ---------------------------------------------------------------------------
__global__ __launch_bounds__(256) void convert_wt(const float* __restrict__ W,
                                                  ushort_t* __restrict__ Ht,
                                                  ushort_t* __restrict__ Lt)
{
    __shared__ float T[64][65];
    const int tid = threadIdx.x;
    const int ty = tid >> 4, tx = tid & 15;
    const int n0 = blockIdx.x * 64, k0 = blockIdx.y * 64;
    #pragma unroll
    for (int i = 0; i < 4; ++i){
        const int kl = ty + i * 16;
        float4 w = *(const float4*)&W[(size_t)(k0 + kl) * EE + n0 + tx * 4];
        T[kl][tx*4 + 0] = w.x; T[kl][tx*4 + 1] = w.y;
        T[kl][tx*4 + 2] = w.z; T[kl][tx*4 + 3] = w.w;
    }
    __syncthreads();
    #pragma unroll
    for (int i = 0; i < 4; ++i){
        const int nl = ty + i * 16;
        ushort4 h, l;
        ushort_t* hp = &h.x; ushort_t* lp = &l.x;
        #pragma unroll
        for (int j = 0; j < 4; ++j){
            const float v = T[tx*4 + j][nl];
            ushort_t hh = f2bf(v);
            hp[j] = hh;
            lp[j] = f2bf(v - bf2f(hh));
        }
        const size_t o = (size_t)(n0 + nl) * EE + k0 + tx * 4;
        *(ushort4*)&Ht[o] = h;
        *(ushort4*)&Lt[o] = l;
    }
}

// ---------------------------------------------------------------------------
// Split-bf16 MFMA GEMM: C = X(4096x1024) @ W(1024x1024) + bias
// MODE 0: Q  -> bf16 hi/lo [bh][s][d]
// MODE 1: K  -> bf16 hi ONLY [bh][s][d], scaled by ts[h]
// MODE 2: V  -> bf16 hi only, transposed [bh][d][s]
// MODE 3: fp32 row-major (final projection -> d_out)
// ---------------------------------------------------------------------------
template<int MODE>
__global__ __launch_bounds__(256) void gemm_mfma(
        const ushort_t* __restrict__ Xh, const ushort_t* __restrict__ Xl,
        const ushort_t* __restrict__ Wth, const ushort_t* __restrict__ Wtl,
        const float* __restrict__ bias, const float* __restrict__ ts,
        float* __restrict__ OutF, ushort_t* __restrict__ OutH,
        ushort_t* __restrict__ OutL)
{
    __shared__ ushort_t buf[2][16384];   // [stage][Ah|Al|Bh|Bl], 32 KB each
    const int tid  = threadIdx.x;
    const int lane = tid & 63, wave = tid >> 6;
    const int c16  = lane & 15, qd = lane >> 4;
    const int m0 = blockIdx.y * 128, n0 = blockIdx.x * 128;
    const int wm = (wave >> 1) * 64, wn = (wave & 1) * 64;
    const int lrow = tid >> 1, lkg = (tid & 1) * 16;

    f32x4 acc[4][4];
    #pragma unroll
    for (int a = 0; a < 4; ++a)
        #pragma unroll
        for (int b = 0; b < 4; ++b) acc[a][b] = (f32x4){0.f,0.f,0.f,0.f};

    {
        const size_t xo = (size_t)(m0 + lrow) * EE + lkg;
        const size_t wo = (size_t)(n0 + lrow) * EE + lkg;
        bf16x8 x0 = *(const bf16x8*)&Xh[xo];
        bf16x8 x1 = *(const bf16x8*)&Xh[xo + 8];
        bf16x8 x2 = *(const bf16x8*)&Xl[xo];
        bf16x8 x3 = *(const bf16x8*)&Xl[xo + 8];
        bf16x8 w0 = *(const bf16x8*)&Wth[wo];
        bf16x8 w1 = *(const bf16x8*)&Wth[wo + 8];
        bf16x8 w2 = *(const bf16x8*)&Wtl[wo];
        bf16x8 w3 = *(const bf16x8*)&Wtl[wo + 8];
        *(bf16x8*)&buf[0][lrow*32 + lkg]          = x0;
        *(bf16x8*)&buf[0][lrow*32 + lkg + 8]      = x1;
        *(bf16x8*)&buf[0][4096 + lrow*32 + lkg]   = x2;
        *(bf16x8*)&buf[0][4096 + lrow*32 + lkg+8] = x3;
        *(bf16x8*)&buf[0][8192 + lrow*32 + lkg]   = w0;
        *(bf16x8*)&buf[0][8192 + lrow*32 + lkg+8] = w1;
        *(bf16x8*)&buf[0][12288 + lrow*32 + lkg]  = w2;
        *(bf16x8*)&buf[0][12288 + lrow*32 + lkg+8]= w3;
    }
    __syncthreads();

    int cur = 0;
    for (int k0 = 0; k0 < EE; k0 += 32){
        const bool more = (k0 + 32) < EE;
        bf16x8 g[8];
        if (more){
            const size_t xo = (size_t)(m0 + lrow) * EE + k0 + 32 + lkg;
            const size_t wo = (size_t)(n0 + lrow) * EE + k0 + 32 + lkg;
            g[0] = *(const bf16x8*)&Xh[xo];  g[1] = *(const bf16x8*)&Xh[xo + 8];
            g[2] = *(const bf16x8*)&Xl[xo];  g[3] = *(const bf16x8*)&Xl[xo + 8];
            g[4] = *(const bf16x8*)&Wth[wo]; g[5] = *(const bf16x8*)&Wth[wo + 8];
            g[6] = *(const bf16x8*)&Wtl[wo]; g[7] = *(const bf16x8*)&Wtl[wo + 8];
        }
        const ushort_t* A0 = &buf[cur][0];
        const ushort_t* A1 = &buf[cur][4096];
        const ushort_t* B0 = &buf[cur][8192];
        const ushort_t* B1 = &buf[cur][12288];
        bf16x8 afh[4], afl[4], bfh[4], bfl[4];
        #pragma unroll
        for (int i = 0; i < 4; ++i){
            afh[i] = *(const bf16x8*)&A0[(wm + i*16 + c16)*32 + qd*8];
            afl[i] = *(const bf16x8*)&A1[(wm + i*16 + c16)*32 + qd*8];
            bfh[i] = *(const bf16x8*)&B0[(wn + i*16 + c16)*32 + qd*8];
            bfl[i] = *(const bf16x8*)&B1[(wn + i*16 + c16)*32 + qd*8];
        }
        #pragma unroll
        for (int a = 0; a < 4; ++a){
            #pragma unroll
            for (int b = 0; b < 4; ++b){
                if (MODE == 2){
                    acc[a][b] = __builtin_amdgcn_mfma_f32_16x16x32_bf16(afh[a], bfh[b], acc[a][b], 0,0,0);
                    acc[a][b] = __builtin_amdgcn_mfma_f32_16x16x32_bf16(afh[a], bfl[b], acc[a][b], 0,0,0);
                    acc[a][b] = __builtin_amdgcn_mfma_f32_16x16x32_bf16(afl[a], bfh[b], acc[a][b], 0,0,0);
                } else {
                    acc[a][b] = __builtin_amdgcn_mfma_f32_16x16x32_bf16(bfh[a], afh[b], acc[a][b], 0,0,0);
                    acc[a][b] = __builtin_amdgcn_mfma_f32_16x16x32_bf16(bfh[a], afl[b], acc[a][b], 0,0,0);
                    acc[a][b] = __builtin_amdgcn_mfma_f32_16x16x32_bf16(bfl[a], afh[b], acc[a][b], 0,0,0);
                }
            }
        }
        if (more){
            ushort_t* N = &buf[cur ^ 1][0];
            *(bf16x8*)&N[lrow*32 + lkg]           = g[0];
            *(bf16x8*)&N[lrow*32 + lkg + 8]       = g[1];
            *(bf16x8*)&N[4096 + lrow*32 + lkg]    = g[2];
            *(bf16x8*)&N[4096 + lrow*32 + lkg+8]  = g[3];
            *(bf16x8*)&N[8192 + lrow*32 + lkg]    = g[4];
            *(bf16x8*)&N[8192 + lrow*32 + lkg+8]  = g[5];
            *(bf16x8*)&N[12288 + lrow*32 + lkg]   = g[6];
            *(bf16x8*)&N[12288 + lrow*32 + lkg+8] = g[7];
            __syncthreads();
            cur ^= 1;
        }
    }

    if (MODE == 3){
        #pragma unroll
        for (int a = 0; a < 4; ++a){
            const int ng = n0 + wn + a*16 + qd*4;
            float4 b4 = *(const float4*)&bias[ng];
            const float bb[4] = {b4.x, b4.y, b4.z, b4.w};
            #pragma unroll
            for (int b = 0; b < 4; ++b){
                const int mg = m0 + wm + b*16 + c16;
                float4 o;
                o.x = acc[a][b][0] + bb[0]; o.y = acc[a][b][1] + bb[1];
                o.z = acc[a][b][2] + bb[2]; o.w = acc[a][b][3] + bb[3];
                *(float4*)&OutF[(size_t)mg * EE + ng] = o;
            }
        }
    } else if (MODE == 0){
        #pragma unroll
        for (int a = 0; a < 4; ++a){
            const int ng = n0 + wn + a*16 + qd*4;
            const int h = ng >> 6, d0 = ng & 63;
            float4 b4 = *(const float4*)&bias[ng];
            const float bb[4] = {b4.x, b4.y, b4.z, b4.w};
            #pragma unroll
            for (int b = 0; b < 4; ++b){
                const int mg = m0 + wm + b*16 + c16;
                const int bi = mg >> 11, s = mg & (SS - 1);
                ushort4 hv, lv;
                ushort_t* hp = &hv.x; ushort_t* lp = &lv.x;
                #pragma unroll
                for (int r = 0; r < 4; ++r){
                    const float v = acc[a][b][r] + bb[r];
                    ushort_t hh = f2bf(v);
                    hp[r] = hh;
                    lp[r] = f2bf(v - bf2f(hh));
                }
                const size_t o = (((size_t)(bi * HH + h)) * SS + s) * DH + d0;
                *(ushort4*)&OutH[o] = hv;
                *(ushort4*)&OutL[o] = lv;
            }
        }
    } else if (MODE == 1){
        #pragma unroll
        for (int a = 0; a < 4; ++a){
            const int ng = n0 + wn + a*16 + qd*4;
            const int h = ng >> 6, d0 = ng & 63;
            const float tsc = ts[h];
            float4 b4 = *(const float4*)&bias[ng];
            const float bb[4] = {b4.x, b4.y, b4.z, b4.w};
            #pragma unroll
            for (int b = 0; b < 4; ++b){
                const int mg = m0 + wm + b*16 + c16;
                const int bi = mg >> 11, s = mg & (SS - 1);
                ushort4 hv;
                ushort_t* hp = &hv.x;
                #pragma unroll
                for (int r = 0; r < 4; ++r)
                    hp[r] = f2bf((acc[a][b][r] + bb[r]) * tsc);
                *(ushort4*)&OutH[(((size_t)(bi * HH + h)) * SS + s) * DH + d0] = hv;
            }
        }
    } else { // MODE 2: V^T hi only
        #pragma unroll
        for (int a = 0; a < 4; ++a){
            const int mg = m0 + wm + a*16 + qd*4;
            const int bi = mg >> 11, s0 = mg & (SS - 1);
            #pragma unroll
            for (int b = 0; b < 4; ++b){
                const int ng = n0 + wn + b*16 + c16;
                const int h = ng >> 6, d = ng & 63;
                const float bv = bias[ng];
                ushort4 hv;
                ushort_t* hp = &hv.x;
                #pragma unroll
                for (int r = 0; r < 4; ++r) hp[r] = f2bf(acc[a][b][r] + bv);
                *(ushort4*)&OutH[(((size_t)(bi * HH + h)) * DH + d) * SS + s0] = hv;
            }
        }
    }
}

// ---------------------------------------------------------------------------
// Fused attention, 512 threads / 8 waves; wave owns 256 score columns.
// Top-k selection: scores (as sortkeys) round-trip through LDS so each wave
// owns one full row; threshold found by 32-step integer bisection where
// count(key >= mid) = popcll(ballot) — zero LDS atomics, zero histogram.
// LDS union: exchange 8 rows x 2048 fp32 (64 KB) | probs | red.
// ---------------------------------------------------------------------------
__global__ __launch_bounds__(512, 4) void attn_kernel(
        const ushort_t* __restrict__ Qh, const ushort_t* __restrict__ Ql,
        const ushort_t* __restrict__ Khi, const ushort_t* __restrict__ Vth,
        ushort_t* __restrict__ AOh, ushort_t* __restrict__ AOl)
{
    __shared__ __align__(16) char uni[65536];
    __shared__ float wsums[8][16];
    __shared__ unsigned thr16[16];

    const int tid  = threadIdx.x;
    const int lane = tid & 63;
    const int wave = tid >> 6;
    const int qd   = lane >> 4;
    const int c16  = lane & 15;
    const unsigned Bx = blockIdx.x;
    const int xcd  = Bx & 7;
    const int qq   = Bx >> 3;
    const int tile = qq & 127;
    const int bh   = (qq >> 7) * 8 + xcd;
    const int t0   = tile * QT;
    const int wbase = wave * 256;

    // ---- Q fragments (pre-split hi/lo) ----
    bf16x8 qh[2], ql[2];
    {
        const size_t qbase = ((size_t)bh * SS + t0 + c16) * DH;
        #pragma unroll
        for (int kc = 0; kc < 2; ++kc){
            qh[kc] = *(const bf16x8*)&Qh[qbase + kc*32 + qd*8];
            ql[kc] = *(const bf16x8*)&Ql[qbase + kc*32 + qd*8];
        }
    }

    // ---- phase 1: scores (K hi-only, Q split) ----
    f32x4 acc[16];
    const ushort_t* Kh = Khi + (size_t)bh * SS * DH;
    #pragma unroll
    for (int t = 0; t < 16; ++t){
        f32x4 a = {0.f, 0.f, 0.f, 0.f};
        const int srow = wbase + t*16 + c16;
        const ushort_t* kp = Kh + (size_t)srow * DH + qd*8;
        #pragma unroll
        for (int kc = 0; kc < 2; ++kc){
            bf16x8 kh = *(const bf16x8*)(kp + kc*32);
            a = __builtin_amdgcn_mfma_f32_16x16x32_bf16(qh[kc], kh, a, 0, 0, 0);
            a = __builtin_amdgcn_mfma_f32_16x16x32_bf16(ql[kc], kh, a, 0, 0, 0);
        }
        acc[t] = a;
    }

    // ---- scale + diag boost, to sortkeys in place ----
    #pragma unroll
    for (int t = 0; t < 16; ++t){
        const int colg = wbase + t*16 + c16;
        #pragma unroll
        for (int r = 0; r < 4; ++r){
            float v = acc[t][r] * 0.15625f;        // 1/8 * 1.25
            if (colg == t0 + qd*4 + r) v *= 1.15f;
            acc[t][r] = __uint_as_float(sortkey(v));
        }
    }

    // ---- phase 2: exact top-k threshold via exchange + wave-local bisection ----
    float* ex = (float*)uni;   // 8 rows x 2048 fp32 (key bits)
    #pragma unroll
    for (int half = 0; half < 2; ++half){
        // stage rows [half*8, half*8+8): held by lanes with qd>>1 == half
        if ((qd >> 1) == half){
            const int rl = (qd & 1) * 4;   // local row base 0 or 4
            #pragma unroll
            for (int t = 0; t < 16; ++t)
                #pragma unroll
                for (int r = 0; r < 4; ++r)
                    ex[(rl + r) * SS + wbase + t*16 + c16] = acc[t][r];
        }
        __syncthreads();
        // wave w owns row half*8 + w; lane holds cols {lane + 64j}
        unsigned cand[32];
        #pragma unroll
        for (int j = 0; j < 32; ++j)
            cand[j] = __float_as_uint(ex[wave * SS + lane + 64*j]);
        unsigned lo = 0u, hi = 0xFFFFFFFFu;
        #pragma unroll 1
        for (int it = 0; it < 32; ++it){
            const unsigned mid = lo + ((hi - lo) >> 1);
            int c = 0;
            #pragma unroll
            for (int j = 0; j < 32; ++j)
                c += (int)__popcll(__ballot(cand[j] >= mid));
            if (c >= KKSEL) lo = mid; else hi = mid;
        }
        if (lane == 0) thr16[half*8 + wave] = lo;
        __syncthreads();   // all reads done before next half's writes / phase 3
    }

    // ---- phase 3: boost + exp + row sums ----
    unsigned thr[4];
    #pragma unroll
    for (int r = 0; r < 4; ++r) thr[r] = thr16[qd*4 + r];
    float psum[4] = {0.f, 0.f, 0.f, 0.f};
    #pragma unroll
    for (int t = 0; t < 16; ++t){
        #pragma unroll
        for (int r = 0; r < 4; ++r){
            const unsigned key = __float_as_uint(acc[t][r]);
            float s = inv_sortkey(key);
            s *= (key >= thr[r]) ? 1.15f : 1.0f;
            const float e = __expf(s);
            acc[t][r] = e;
            psum[r] += e;
        }
    }
    #pragma unroll
    for (int off = 1; off <= 8; off <<= 1){
        #pragma unroll
        for (int r = 0; r < 4; ++r) psum[r] += __shfl_xor(psum[r], off, 64);
    }
    if (c16 == 0){
        #pragma unroll
        for (int r = 0; r < 4; ++r) wsums[wave][qd*4 + r] = psum[r];
    }
    __syncthreads();
    float pinv[4];
    #pragma unroll
    for (int r = 0; r < 4; ++r){
        const int row = qd*4 + r;
        float s = 0.f;
        #pragma unroll
        for (int w = 0; w < 8; ++w) s += wsums[w][row];
        pinv[r] = 1.f / s;
    }

    // ---- phase 4: O = P @ V (two 128-col halves per wave) ----
    const ushort_t* Vh = Vth + (size_t)bh * DH * SS;
    ushort_t* pw = (ushort_t*)uni + wave * (QT * PST);   // per-wave region
    f32x4 oacc[4];
    #pragma unroll
    for (int dt = 0; dt < 4; ++dt) oacc[dt] = (f32x4){0.f, 0.f, 0.f, 0.f};

    #pragma unroll
    for (int half = 0; half < 2; ++half){
        #pragma unroll
        for (int tt = 0; tt < 8; ++tt){
            const int t = half*8 + tt;
            #pragma unroll
            for (int r = 0; r < 4; ++r)
                pw[(qd*4 + r) * PST + tt*16 + c16] = f2bf(acc[t][r] * pinv[r]);
        }
        // per-wave region: same-wave ds_write -> ds_read, no barrier needed
        #pragma unroll
        for (int kc = 0; kc < 4; ++kc){
            bf16x8 pf = *(const bf16x8*)&pw[c16 * PST + kc*32 + qd*8];
            const int sbase = wbase + half*128 + kc*32 + qd*8;
            #pragma unroll
            for (int dt = 0; dt < 4; ++dt){
                const int d = dt*16 + c16;
                bf16x8 vh = *(const bf16x8*)(Vh + (size_t)d * SS + sbase);
                oacc[dt] = __builtin_amdgcn_mfma_f32_16x16x32_bf16(pf, vh, oacc[dt], 0, 0, 0);
            }
        }
    }

    // ---- cross-wave O reduction + split-bf16 store ----
    __syncthreads();   // all probs reads done before red overwrites the union
    float* red = (float*)uni;   // 8 x 16 x 65
    #pragma unroll
    for (int dt = 0; dt < 4; ++dt)
        #pragma unroll
        for (int r = 0; r < 4; ++r)
            red[(wave*16 + qd*4 + r) * 65 + dt*16 + c16] = oacc[dt][r];
    __syncthreads();

    const int b = bh >> 4, h = bh & 15;
    if (tid < 256){
        const int r  = tid >> 4;
        const int c4 = (tid & 15) * 4;
        ushort4 oh, ol;
        ushort_t* ohp = &oh.x; ushort_t* olp = &ol.x;
        #pragma unroll
        for (int j = 0; j < 4; ++j){
            float s = 0.f;
            #pragma unroll
            for (int w = 0; w < 8; ++w) s += red[(w*16 + r) * 65 + c4 + j];
            ushort_t hh = f2bf(s);
            ohp[j] = hh;
            olp[j] = f2bf(s - bf2f(hh));
        }
        const size_t o = ((size_t)b * SS + t0 + r) * EE + h*DH + c4;
        *(ushort4*)&AOh[o] = oh;
        *(ushort4*)&AOl[o] = ol;
    }
}

// ---------------------------------------------------------------------------
extern "C" void kernel_launch(void* const* d_in, const int* in_sizes, int n_in,
                              void* d_out, int out_size, void* d_ws, size_t ws_size,
                              hipStream_t stream)
{
    const float* query = (const float*)d_in[0];
    const float* key   = (const float*)d_in[1];
    const float* value = (const float*)d_in[2];
    const float* Wq    = (const float*)d_in[3];
    const float* bq    = (const float*)d_in[4];
    const float* Wk    = (const float*)d_in[5];
    const float* bk    = (const float*)d_in[6];
    const float* Wv    = (const float*)d_in[7];
    const float* bv    = (const float*)d_in[8];
    const float* Wo    = (const float*)d_in[9];
    const float* bo    = (const float*)d_in[10];
    const float* ts    = (const float*)d_in[11];
    float* out = (float*)d_out;
    char* w = (char*)d_ws;

    const size_t MB = 1u << 20;
    ushort_t* Qh  = (ushort_t*)(w + 0 * MB);
    ushort_t* Ql  = (ushort_t*)(w + 8 * MB);
    ushort_t* Kh  = (ushort_t*)(w + 16 * MB);
    ushort_t* Vth = (ushort_t*)(w + 24 * MB);
    ushort_t* Xh  = (ushort_t*)(w + 32 * MB);  // aliased: X-split scratch, then AOh
    ushort_t* Xl  = (ushort_t*)(w + 40 * MB);  // aliased: X-split scratch, then AOl
    ushort_t* Wth = (ushort_t*)(w + 48 * MB);
    ushort_t* Wtl = (ushort_t*)(w + 50 * MB);

    dim3 cb(256);
    dim3 cxg(4096);            // convert_x: 4M elems / (256*4)
    dim3 wtg(16, 16);          // convert_wt: 64x64 tiles
    dim3 gg(8, 32), gb(256);   // gemm: N/128 x M/128

    // Q projection
    hipLaunchKernelGGL(convert_x, cxg, cb, 0, stream, query, Xh, Xl);
    hipLaunchKernelGGL(convert_wt, wtg, cb, 0, stream, Wq, Wth, Wtl);
    hipLaunchKernelGGL((gemm_mfma<0>), gg, gb, 0, stream, Xh, Xl, Wth, Wtl, bq, nullptr,
                       nullptr, Qh, Ql);
    // K projection (scaled, hi only)
    hipLaunchKernelGGL(convert_x, cxg, cb, 0, stream, key, Xh, Xl);
    hipLaunchKernelGGL(convert_wt, wtg, cb, 0, stream, Wk, Wth, Wtl);
    hipLaunchKernelGGL((gemm_mfma<1>), gg, gb, 0, stream, Xh, Xl, Wth, Wtl, bk, ts,
                       nullptr, Kh, nullptr);
    // V projection (transposed, hi only)
    hipLaunchKernelGGL(convert_x, cxg, cb, 0, stream, value, Xh, Xl);
    hipLaunchKernelGGL(convert_wt, wtg, cb, 0, stream, Wv, Wth, Wtl);
    hipLaunchKernelGGL((gemm_mfma<2>), gg, gb, 0, stream, Xh, Xl, Wth, Wtl, bv, nullptr,
                       nullptr, Vth, nullptr);
    // attention (writes AO split into Xh/Xl region)
    hipLaunchKernelGGL(attn_kernel, dim3(BB * HH * (SS / QT)), dim3(512), 0, stream,
                       Qh, Ql, Kh, Vth, Xh, Xl);
    // output projection
    hipLaunchKernelGGL(convert_wt, wtg, cb, 0, stream, Wo, Wth, Wtl);
    hipLaunchKernelGGL((gemm_mfma<3>), gg, gb, 0, stream, Xh, Xl, Wth, Wtl, bo, nullptr,
                       out, nullptr, nullptr);
}

// Round 6
// 703.031 us; speedup vs baseline: 2.5116x; 1.1092x over previous
//
#include <hip/hip_runtime.h>
#include <cstdint>
#include <cstddef>

#define BB 2
#define SS 2048
#define EE 1024
#define HH 16
#define DH 64
#define KKSEL 409   // kk = int(2048*0.2)
#define QT 16       // query rows per attention block
#define PST 136     // probs LDS row stride (bf16 elems) per half (128 cols + pad)

typedef __attribute__((ext_vector_type(8))) short bf16x8;
typedef __attribute__((ext_vector_type(4))) float f32x4;
typedef unsigned short ushort_t;

__device__ __forceinline__ unsigned short f2bf(float f){
    unsigned u = __float_as_uint(f);
    u += 0x7fffu + ((u >> 16) & 1u);          // RNE
    return (unsigned short)(u >> 16);
}
__device__ __forceinline__ float bf2f(unsigned short h){
    return __uint_as_float(((unsigned)h) << 16);
}
__device__ __forceinline__ unsigned sortkey(float f){
    unsigned u = __float_as_uint(f);
    return (u & 0x80000000u) ? ~u : (u | 0x80000000u);
}
__device__ __forceinline__ float inv_sortkey(unsigned k){
    unsigned u = (k & 0x80000000u) ? (k & 0x7fffffffu) : ~k;
    return __uint_as_float(u);
}
__device__ __forceinline__ void split8(const float* f, bf16x8& h, bf16x8& l){
    #pragma unroll
    for (int j = 0; j < 8; ++j){
        ushort_t hh = f2bf(f[j]);
        h[j] = (short)hh;
        l[j] = (short)f2bf(f[j] - bf2f(hh));
    }
}

// ---------------------------------------------------------------------------
// convert_wt: W (1024x1024 [k][n]) -> W^T bf16 hi/lo ([n][k])
// ---------------------------------------------------------------------------
__global__ __launch_bounds__(256) void convert_wt(const float* __restrict__ W,
                                                  ushort_t* __restrict__ Ht,
                                                  ushort_t* __restrict__ Lt)
{
    __shared__ float T[64][65];
    const int tid = threadIdx.x;
    const int ty = tid >> 4, tx = tid & 15;
    const int n0 = blockIdx.x * 64, k0 = blockIdx.y * 64;
    #pragma unroll
    for (int i = 0; i < 4; ++i){
        const int kl = ty + i * 16;
        float4 w = *(const float4*)&W[(size_t)(k0 + kl) * EE + n0 + tx * 4];
        T[kl][tx*4 + 0] = w.x; T[kl][tx*4 + 1] = w.y;
        T[kl][tx*4 + 2] = w.z; T[kl][tx*4 + 3] = w.w;
    }
    __syncthreads();
    #pragma unroll
    for (int i = 0; i < 4; ++i){
        const int nl = ty + i * 16;
        ushort4 h, l;
        ushort_t* hp = &h.x; ushort_t* lp = &l.x;
        #pragma unroll
        for (int j = 0; j < 4; ++j){
            const float v = T[tx*4 + j][nl];
            ushort_t hh = f2bf(v);
            hp[j] = hh;
            lp[j] = f2bf(v - bf2f(hh));
        }
        const size_t o = (size_t)(n0 + nl) * EE + k0 + tx * 4;
        *(ushort4*)&Ht[o] = h;
        *(ushort4*)&Lt[o] = l;
    }
}

// ---------------------------------------------------------------------------
// Split-bf16 MFMA GEMM with fused X conversion:
// C = X(4096x1024, fp32) @ W(1024x1024) + bias
// X staged fp32 -> split hi/lo bf16 in registers -> LDS.
// W given pre-split/transposed bf16 [n][k] (convert_wt).
// acc = Xh*Wh + Xh*Wl + Xl*Wh
// MODE 0: Q  -> bf16 hi/lo [bh][s][d]
// MODE 1: K  -> bf16 hi only [bh][s][d], scaled by ts[h]
// MODE 2: V  -> bf16 hi only, transposed [bh][d][s]
// MODE 3: fp32 row-major (final projection -> d_out)
// ---------------------------------------------------------------------------
template<int MODE>
__global__ __launch_bounds__(256) void gemm_mfma(
        const float* __restrict__ X,
        const ushort_t* __restrict__ Wth, const ushort_t* __restrict__ Wtl,
        const float* __restrict__ bias, const float* __restrict__ ts,
        float* __restrict__ OutF, ushort_t* __restrict__ OutH,
        ushort_t* __restrict__ OutL)
{
    __shared__ ushort_t buf[2][16384];   // [stage][Ah|Al|Bh|Bl], 32 KB each
    const int tid  = threadIdx.x;
    const int lane = tid & 63, wave = tid >> 6;
    const int c16  = lane & 15, qd = lane >> 4;
    const int m0 = blockIdx.y * 128, n0 = blockIdx.x * 128;
    const int wm = (wave >> 1) * 64, wn = (wave & 1) * 64;
    const int lrow = tid >> 1, lkg = (tid & 1) * 16;

    f32x4 acc[4][4];
    #pragma unroll
    for (int a = 0; a < 4; ++a)
        #pragma unroll
        for (int b = 0; b < 4; ++b) acc[a][b] = (f32x4){0.f,0.f,0.f,0.f};

    const float* Xr = X + (size_t)(m0 + lrow) * EE + lkg;
    const ushort_t* Whr = Wth + (size_t)(n0 + lrow) * EE + lkg;
    const ushort_t* Wlr = Wtl + (size_t)(n0 + lrow) * EE + lkg;

    // prologue: stage k0 = 0 into buf[0]
    {
        float fx[16];
        *(float4*)&fx[0]  = *(const float4*)&Xr[0];
        *(float4*)&fx[4]  = *(const float4*)&Xr[4];
        *(float4*)&fx[8]  = *(const float4*)&Xr[8];
        *(float4*)&fx[12] = *(const float4*)&Xr[12];
        bf16x8 w0 = *(const bf16x8*)&Whr[0];
        bf16x8 w1 = *(const bf16x8*)&Whr[8];
        bf16x8 w2 = *(const bf16x8*)&Wlr[0];
        bf16x8 w3 = *(const bf16x8*)&Wlr[8];
        bf16x8 h0, l0, h1, l1;
        split8(fx, h0, l0); split8(fx + 8, h1, l1);
        *(bf16x8*)&buf[0][lrow*32 + lkg]           = h0;
        *(bf16x8*)&buf[0][lrow*32 + lkg + 8]       = h1;
        *(bf16x8*)&buf[0][4096 + lrow*32 + lkg]    = l0;
        *(bf16x8*)&buf[0][4096 + lrow*32 + lkg+8]  = l1;
        *(bf16x8*)&buf[0][8192 + lrow*32 + lkg]    = w0;
        *(bf16x8*)&buf[0][8192 + lrow*32 + lkg+8]  = w1;
        *(bf16x8*)&buf[0][12288 + lrow*32 + lkg]   = w2;
        *(bf16x8*)&buf[0][12288 + lrow*32 + lkg+8] = w3;
    }
    __syncthreads();

    int cur = 0;
    for (int k0 = 0; k0 < EE; k0 += 32){
        const bool more = (k0 + 32) < EE;
        float fx[16];
        bf16x8 gw[4];
        if (more){
            const float* xp = Xr + k0 + 32;
            *(float4*)&fx[0]  = *(const float4*)&xp[0];
            *(float4*)&fx[4]  = *(const float4*)&xp[4];
            *(float4*)&fx[8]  = *(const float4*)&xp[8];
            *(float4*)&fx[12] = *(const float4*)&xp[12];
            gw[0] = *(const bf16x8*)&Whr[k0 + 32];
            gw[1] = *(const bf16x8*)&Whr[k0 + 40];
            gw[2] = *(const bf16x8*)&Wlr[k0 + 32];
            gw[3] = *(const bf16x8*)&Wlr[k0 + 40];
        }
        const ushort_t* A0 = &buf[cur][0];
        const ushort_t* A1 = &buf[cur][4096];
        const ushort_t* B0 = &buf[cur][8192];
        const ushort_t* B1 = &buf[cur][12288];
        bf16x8 afh[4], afl[4], bfh[4], bfl[4];
        #pragma unroll
        for (int i = 0; i < 4; ++i){
            afh[i] = *(const bf16x8*)&A0[(wm + i*16 + c16)*32 + qd*8];
            afl[i] = *(const bf16x8*)&A1[(wm + i*16 + c16)*32 + qd*8];
            bfh[i] = *(const bf16x8*)&B0[(wn + i*16 + c16)*32 + qd*8];
            bfl[i] = *(const bf16x8*)&B1[(wn + i*16 + c16)*32 + qd*8];
        }
        #pragma unroll
        for (int a = 0; a < 4; ++a){
            #pragma unroll
            for (int b = 0; b < 4; ++b){
                if (MODE == 2){   // X first: D rows <- s
                    acc[a][b] = __builtin_amdgcn_mfma_f32_16x16x32_bf16(afh[a], bfh[b], acc[a][b], 0,0,0);
                    acc[a][b] = __builtin_amdgcn_mfma_f32_16x16x32_bf16(afh[a], bfl[b], acc[a][b], 0,0,0);
                    acc[a][b] = __builtin_amdgcn_mfma_f32_16x16x32_bf16(afl[a], bfh[b], acc[a][b], 0,0,0);
                } else {          // W first: D rows <- n
                    acc[a][b] = __builtin_amdgcn_mfma_f32_16x16x32_bf16(bfh[a], afh[b], acc[a][b], 0,0,0);
                    acc[a][b] = __builtin_amdgcn_mfma_f32_16x16x32_bf16(bfh[a], afl[b], acc[a][b], 0,0,0);
                    acc[a][b] = __builtin_amdgcn_mfma_f32_16x16x32_bf16(bfl[a], afh[b], acc[a][b], 0,0,0);
                }
            }
        }
        if (more){
            bf16x8 h0, l0, h1, l1;
            split8(fx, h0, l0); split8(fx + 8, h1, l1);
            ushort_t* N = &buf[cur ^ 1][0];
            *(bf16x8*)&N[lrow*32 + lkg]           = h0;
            *(bf16x8*)&N[lrow*32 + lkg + 8]       = h1;
            *(bf16x8*)&N[4096 + lrow*32 + lkg]    = l0;
            *(bf16x8*)&N[4096 + lrow*32 + lkg+8]  = l1;
            *(bf16x8*)&N[8192 + lrow*32 + lkg]    = gw[0];
            *(bf16x8*)&N[8192 + lrow*32 + lkg+8]  = gw[1];
            *(bf16x8*)&N[12288 + lrow*32 + lkg]   = gw[2];
            *(bf16x8*)&N[12288 + lrow*32 + lkg+8] = gw[3];
            __syncthreads();
            cur ^= 1;
        }
    }

    if (MODE == 3){
        #pragma unroll
        for (int a = 0; a < 4; ++a){
            const int ng = n0 + wn + a*16 + qd*4;
            float4 b4 = *(const float4*)&bias[ng];
            const float bb[4] = {b4.x, b4.y, b4.z, b4.w};
            #pragma unroll
            for (int b = 0; b < 4; ++b){
                const int mg = m0 + wm + b*16 + c16;
                float4 o;
                o.x = acc[a][b][0] + bb[0]; o.y = acc[a][b][1] + bb[1];
                o.z = acc[a][b][2] + bb[2]; o.w = acc[a][b][3] + bb[3];
                *(float4*)&OutF[(size_t)mg * EE + ng] = o;
            }
        }
    } else if (MODE == 0){
        #pragma unroll
        for (int a = 0; a < 4; ++a){
            const int ng = n0 + wn + a*16 + qd*4;
            const int h = ng >> 6, d0 = ng & 63;
            float4 b4 = *(const float4*)&bias[ng];
            const float bb[4] = {b4.x, b4.y, b4.z, b4.w};
            #pragma unroll
            for (int b = 0; b < 4; ++b){
                const int mg = m0 + wm + b*16 + c16;
                const int bi = mg >> 11, s = mg & (SS - 1);
                ushort4 hv, lv;
                ushort_t* hp = &hv.x; ushort_t* lp = &lv.x;
                #pragma unroll
                for (int r = 0; r < 4; ++r){
                    const float v = acc[a][b][r] + bb[r];
                    ushort_t hh = f2bf(v);
                    hp[r] = hh;
                    lp[r] = f2bf(v - bf2f(hh));
                }
                const size_t o = (((size_t)(bi * HH + h)) * SS + s) * DH + d0;
                *(ushort4*)&OutH[o] = hv;
                *(ushort4*)&OutL[o] = lv;
            }
        }
    } else if (MODE == 1){
        #pragma unroll
        for (int a = 0; a < 4; ++a){
            const int ng = n0 + wn + a*16 + qd*4;
            const int h = ng >> 6, d0 = ng & 63;
            const float tsc = ts[h];
            float4 b4 = *(const float4*)&bias[ng];
            const float bb[4] = {b4.x, b4.y, b4.z, b4.w};
            #pragma unroll
            for (int b = 0; b < 4; ++b){
                const int mg = m0 + wm + b*16 + c16;
                const int bi = mg >> 11, s = mg & (SS - 1);
                ushort4 hv;
                ushort_t* hp = &hv.x;
                #pragma unroll
                for (int r = 0; r < 4; ++r)
                    hp[r] = f2bf((acc[a][b][r] + bb[r]) * tsc);
                *(ushort4*)&OutH[(((size_t)(bi * HH + h)) * SS + s) * DH + d0] = hv;
            }
        }
    } else { // MODE 2: V^T hi only
        #pragma unroll
        for (int a = 0; a < 4; ++a){
            const int mg = m0 + wm + a*16 + qd*4;
            const int bi = mg >> 11, s0 = mg & (SS - 1);
            #pragma unroll
            for (int b = 0; b < 4; ++b){
                const int ng = n0 + wn + b*16 + c16;
                const int h = ng >> 6, d = ng & 63;
                const float bv = bias[ng];
                ushort4 hv;
                ushort_t* hp = &hv.x;
                #pragma unroll
                for (int r = 0; r < 4; ++r) hp[r] = f2bf(acc[a][b][r] + bv);
                *(ushort4*)&OutH[(((size_t)(bi * HH + h)) * DH + d) * SS + s0] = hv;
            }
        }
    }
}

// ---------------------------------------------------------------------------
// Fused attention, 512 threads / 8 waves; wave owns 256 score columns.
// Top-k threshold: LDS exchange so each wave owns full rows, then integer
// bisection; count via inline-asm v_cmp + s_bcnt1 (1 VALU + SALU per cand),
// early exit when count == kk (exact: any separating mid reproduces the
// reference's >= min_topk set; ties fall through to the full 32 iters).
// ---------------------------------------------------------------------------
__global__ __launch_bounds__(512, 4) void attn_kernel(
        const ushort_t* __restrict__ Qh, const ushort_t* __restrict__ Ql,
        const ushort_t* __restrict__ Khi, const ushort_t* __restrict__ Vth,
        float* __restrict__ AO)
{
    __shared__ __align__(16) char uni[65536];
    __shared__ float wsums[8][16];
    __shared__ unsigned thr16[16];

    const int tid  = threadIdx.x;
    const int lane = tid & 63;
    const int wave = tid >> 6;
    const int qd   = lane >> 4;
    const int c16  = lane & 15;
    const unsigned Bx = blockIdx.x;
    const int xcd  = Bx & 7;
    const int qq   = Bx >> 3;
    const int tile = qq & 127;
    const int bh   = (qq >> 7) * 8 + xcd;
    const int t0   = tile * QT;
    const int wbase = wave * 256;

    // ---- Q fragments (pre-split hi/lo) ----
    bf16x8 qh[2], ql[2];
    {
        const size_t qbase = ((size_t)bh * SS + t0 + c16) * DH;
        #pragma unroll
        for (int kc = 0; kc < 2; ++kc){
            qh[kc] = *(const bf16x8*)&Qh[qbase + kc*32 + qd*8];
            ql[kc] = *(const bf16x8*)&Ql[qbase + kc*32 + qd*8];
        }
    }

    // ---- phase 1: scores (K hi-only, Q split) ----
    f32x4 acc[16];
    const ushort_t* Kh = Khi + (size_t)bh * SS * DH;
    #pragma unroll
    for (int t = 0; t < 16; ++t){
        f32x4 a = {0.f, 0.f, 0.f, 0.f};
        const int srow = wbase + t*16 + c16;
        const ushort_t* kp = Kh + (size_t)srow * DH + qd*8;
        #pragma unroll
        for (int kc = 0; kc < 2; ++kc){
            bf16x8 kh = *(const bf16x8*)(kp + kc*32);
            a = __builtin_amdgcn_mfma_f32_16x16x32_bf16(qh[kc], kh, a, 0, 0, 0);
            a = __builtin_amdgcn_mfma_f32_16x16x32_bf16(ql[kc], kh, a, 0, 0, 0);
        }
        acc[t] = a;
    }

    // ---- scale + diag boost, to sortkeys in place ----
    #pragma unroll
    for (int t = 0; t < 16; ++t){
        const int colg = wbase + t*16 + c16;
        #pragma unroll
        for (int r = 0; r < 4; ++r){
            float v = acc[t][r] * 0.15625f;        // 1/8 * 1.25
            if (colg == t0 + qd*4 + r) v *= 1.15f;
            acc[t][r] = __uint_as_float(sortkey(v));
        }
    }

    // ---- phase 2: exact top-k threshold (exchange + bisection) ----
    float* ex = (float*)uni;   // 8 rows x 2048 fp32 (key bits)
    #pragma unroll
    for (int half = 0; half < 2; ++half){
        if ((qd >> 1) == half){
            const int rl = (qd & 1) * 4;
            #pragma unroll
            for (int t = 0; t < 16; ++t)
                #pragma unroll
                for (int r = 0; r < 4; ++r)
                    ex[(rl + r) * SS + wbase + t*16 + c16] = acc[t][r];
        }
        __syncthreads();
        unsigned cand[32];
        #pragma unroll
        for (int j = 0; j < 32; ++j)
            cand[j] = __float_as_uint(ex[wave * SS + lane + 64*j]);
        unsigned lo = sortkey(-64.0f), hi = sortkey(64.0f);   // span < 2^31.1
        #pragma unroll 1
        for (int it = 0; it < 32; ++it){
            const unsigned mid = lo + ((hi - lo) >> 1);
            int c = 0;
            #pragma unroll
            for (int j = 0; j < 32; ++j){
                int pc;
                asm("v_cmp_le_u32 vcc, %1, %2\n\t"
                    "s_bcnt1_i32_b64 %0, vcc"
                    : "=s"(pc) : "s"(mid), "v"(cand[j]) : "vcc");
                c += pc;
            }
            if (c == KKSEL){ lo = mid; break; }
            if (c > KKSEL) lo = mid; else hi = mid;
        }
        if (lane == 0) thr16[half*8 + wave] = lo;
        __syncthreads();
    }

    // ---- phase 3: boost + exp + row sums ----
    unsigned thr[4];
    #pragma unroll
    for (int r = 0; r < 4; ++r) thr[r] = thr16[qd*4 + r];
    float psum[4] = {0.f, 0.f, 0.f, 0.f};
    #pragma unroll
    for (int t = 0; t < 16; ++t){
        #pragma unroll
        for (int r = 0; r < 4; ++r){
            const unsigned key = __float_as_uint(acc[t][r]);
            float s = inv_sortkey(key);
            s *= (key >= thr[r]) ? 1.15f : 1.0f;
            const float e = __expf(s);
            acc[t][r] = e;
            psum[r] += e;
        }
    }
    #pragma unroll
    for (int off = 1; off <= 8; off <<= 1){
        #pragma unroll
        for (int r = 0; r < 4; ++r) psum[r] += __shfl_xor(psum[r], off, 64);
    }
    if (c16 == 0){
        #pragma unroll
        for (int r = 0; r < 4; ++r) wsums[wave][qd*4 + r] = psum[r];
    }
    __syncthreads();
    float pinv[4];
    #pragma unroll
    for (int r = 0; r < 4; ++r){
        const int row = qd*4 + r;
        float s = 0.f;
        #pragma unroll
        for (int w = 0; w < 8; ++w) s += wsums[w][row];
        pinv[r] = 1.f / s;
    }

    // ---- phase 4: O = P @ V (two 128-col halves per wave) ----
    const ushort_t* Vh = Vth + (size_t)bh * DH * SS;
    ushort_t* pw = (ushort_t*)uni + wave * (QT * PST);   // per-wave region
    f32x4 oacc[4];
    #pragma unroll
    for (int dt = 0; dt < 4; ++dt) oacc[dt] = (f32x4){0.f, 0.f, 0.f, 0.f};

    #pragma unroll
    for (int half = 0; half < 2; ++half){
        #pragma unroll
        for (int tt = 0; tt < 8; ++tt){
            const int t = half*8 + tt;
            #pragma unroll
            for (int r = 0; r < 4; ++r)
                pw[(qd*4 + r) * PST + tt*16 + c16] = f2bf(acc[t][r] * pinv[r]);
        }
        // per-wave region: same-wave ds_write -> ds_read, no barrier needed
        #pragma unroll
        for (int kc = 0; kc < 4; ++kc){
            bf16x8 pf = *(const bf16x8*)&pw[c16 * PST + kc*32 + qd*8];
            const int sbase = wbase + half*128 + kc*32 + qd*8;
            #pragma unroll
            for (int dt = 0; dt < 4; ++dt){
                const int d = dt*16 + c16;
                bf16x8 vh = *(const bf16x8*)(Vh + (size_t)d * SS + sbase);
                oacc[dt] = __builtin_amdgcn_mfma_f32_16x16x32_bf16(pf, vh, oacc[dt], 0, 0, 0);
            }
        }
    }

    // ---- cross-wave O reduction + fp32 store ----
    __syncthreads();   // all probs reads done before red overwrites the union
    float* red = (float*)uni;   // 8 x 16 x 65
    #pragma unroll
    for (int dt = 0; dt < 4; ++dt)
        #pragma unroll
        for (int r = 0; r < 4; ++r)
            red[(wave*16 + qd*4 + r) * 65 + dt*16 + c16] = oacc[dt][r];
    __syncthreads();

    const int b = bh >> 4, h = bh & 15;
    {
        const int r  = tid >> 5;           // 0..15
        const int c2 = (tid & 31) * 2;     // 0,2,..,62
        float s0 = 0.f, s1 = 0.f;
        #pragma unroll
        for (int w = 0; w < 8; ++w){
            s0 += red[(w*16 + r) * 65 + c2];
            s1 += red[(w*16 + r) * 65 + c2 + 1];
        }
        float2 o; o.x = s0; o.y = s1;
        *(float2*)&AO[((size_t)b * SS + t0 + r) * EE + h*DH + c2] = o;
    }
}

// ---------------------------------------------------------------------------
extern "C" void kernel_launch(void* const* d_in, const int* in_sizes, int n_in,
                              void* d_out, int out_size, void* d_ws, size_t ws_size,
                              hipStream_t stream)
{
    const float* query = (const float*)d_in[0];
    const float* key   = (const float*)d_in[1];
    const float* value = (const float*)d_in[2];
    const float* Wq    = (const float*)d_in[3];
    const float* bq    = (const float*)d_in[4];
    const float* Wk    = (const float*)d_in[5];
    const float* bk    = (const float*)d_in[6];
    const float* Wv    = (const float*)d_in[7];
    const float* bv    = (const float*)d_in[8];
    const float* Wo    = (const float*)d_in[9];
    const float* bo    = (const float*)d_in[10];
    const float* ts    = (const float*)d_in[11];
    float* out = (float*)d_out;
    char* w = (char*)d_ws;

    const size_t MB = 1u << 20;
    ushort_t* Qh  = (ushort_t*)(w + 0 * MB);
    ushort_t* Ql  = (ushort_t*)(w + 8 * MB);
    ushort_t* Kh  = (ushort_t*)(w + 16 * MB);
    ushort_t* Vth = (ushort_t*)(w + 24 * MB);
    float*    AOw = (float*)   (w + 32 * MB);   // 16 MB fp32
    ushort_t* Wth = (ushort_t*)(w + 48 * MB);
    ushort_t* Wtl = (ushort_t*)(w + 50 * MB);

    dim3 cb(256);
    dim3 wtg(16, 16);          // convert_wt: 64x64 tiles
    dim3 gg(8, 32), gb(256);   // gemm: N/128 x M/128

    // Q projection (fused fp32->split staging)
    hipLaunchKernelGGL(convert_wt, wtg, cb, 0, stream, Wq, Wth, Wtl);
    hipLaunchKernelGGL((gemm_mfma<0>), gg, gb, 0, stream, query, Wth, Wtl, bq, nullptr,
                       nullptr, Qh, Ql);
    // K projection (scaled, hi only)
    hipLaunchKernelGGL(convert_wt, wtg, cb, 0, stream, Wk, Wth, Wtl);
    hipLaunchKernelGGL((gemm_mfma<1>), gg, gb, 0, stream, key, Wth, Wtl, bk, ts,
                       nullptr, Kh, nullptr);
    // V projection (transposed, hi only)
    hipLaunchKernelGGL(convert_wt, wtg, cb, 0, stream, Wv, Wth, Wtl);
    hipLaunchKernelGGL((gemm_mfma<2>), gg, gb, 0, stream, value, Wth, Wtl, bv, nullptr,
                       nullptr, Vth, nullptr);
    // attention -> AO fp32
    hipLaunchKernelGGL(attn_kernel, dim3(BB * HH * (SS / QT)), dim3(512), 0, stream,
                       Qh, Ql, Kh, Vth, AOw);
    // output projection
    hipLaunchKernelGGL(convert_wt, wtg, cb, 0, stream, Wo, Wth, Wtl);
    hipLaunchKernelGGL((gemm_mfma<3>), gg, gb, 0, stream, AOw, Wth, Wtl, bo, nullptr,
                       out, nullptr, nullptr);
}